// Round 18
// baseline (1283.514 us; speedup 1.0000x reference)
//
#include <hip/hip_runtime.h>
#include <hip/hip_bf16.h>
#include <stdint.h>

#define VV 32000
#define HH 128
#define BB 8
#define SS 512
#define NNODE 50000
#define NEDGE 600000
#define NWORK 240          // worker blocks in front kernel (248 total <= 256 CUs)

typedef __attribute__((ext_vector_type(8))) short s16x8;
typedef __attribute__((ext_vector_type(4))) float f32x4;

__device__ __forceinline__ void workers_barrier(int* bar, int tid) {
  __syncthreads();
  if (tid == 0) {
    int g = __hip_atomic_load(&bar[32], __ATOMIC_ACQUIRE, __HIP_MEMORY_SCOPE_AGENT);
    int old = __hip_atomic_fetch_add(&bar[0], 1, __ATOMIC_ACQ_REL, __HIP_MEMORY_SCOPE_AGENT);
    if (old == NWORK-1) {
      __hip_atomic_store(&bar[0], 0, __ATOMIC_RELAXED, __HIP_MEMORY_SCOPE_AGENT);
      __hip_atomic_store(&bar[32], g+1, __ATOMIC_RELEASE, __HIP_MEMORY_SCOPE_AGENT);
    } else {
      while (__hip_atomic_load(&bar[32], __ATOMIC_ACQUIRE, __HIP_MEMORY_SCOPE_AGENT) == g)
        __builtin_amdgcn_s_sleep(32);
    }
  }
  __syncthreads();
}

__device__ __forceinline__ int ntload_i(const int* p) {
  return __builtin_nontemporal_load(p);
}
__device__ __forceinline__ float ntload_f(const float* p) {
  return __builtin_nontemporal_load(p);
}

// ---------------- embedding gather + encoder input-gate GEMM (serial, ~20us) ----
__global__ __launch_bounds__(256) void xg_enc_kernel(
    const int* __restrict__ jin, const float* __restrict__ emb,
    const float* __restrict__ Wih, const float* __restrict__ bvec,
    float* __restrict__ xg)
{
  __shared__ __align__(16) float arow[8][128];
  const int tid = threadIdx.x, blk = blockIdx.x;
  {
    int r = tid >> 5, c = (tid & 31) << 2;
    int tok = jin[blk*8 + r];
    *(float4*)&arow[r][c] = *(const float4*)&emb[(size_t)tok*HH + c];
  }
  __syncthreads();
  const int g0 = tid * 2;
  const float* w0 = Wih + (size_t)g0*HH;
  const float* w1 = w0 + HH;
  float acc0[8], acc1[8];
  #pragma unroll
  for (int r=0;r<8;r++){ acc0[r]=0.f; acc1[r]=0.f; }
  for (int k=0;k<HH;k+=4) {
    float4 wa = *(const float4*)&w0[k];
    float4 wb = *(const float4*)&w1[k];
    #pragma unroll
    for (int r=0;r<8;r++) {
      float4 av = *(const float4*)&arow[r][k];
      acc0[r] += av.x*wa.x + av.y*wa.y + av.z*wa.z + av.w*wa.w;
      acc1[r] += av.x*wb.x + av.y*wb.y + av.z*wb.z + av.w*wb.w;
    }
  }
  float bb0 = bvec[g0], bb1 = bvec[g0+1];
  #pragma unroll
  for (int r=0;r<8;r++) {
    size_t row = (size_t)blk*8 + r;
    xg[row*512 + g0]     = acc0[r] + bb0;
    xg[row*512 + g0 + 1] = acc1[r] + bb1;
  }
}

// ---------------- FRONT: clean enc scan (blocks 0-7) + workers (split + graph) ----
// Worker global READS are non-temporal: graph gathers must not allocate in L2
// and evict the scan blocks' W_hh working set. Atomics stay normal (RMW).
__global__ __launch_bounds__(512) void front_kernel(
    const float* __restrict__ xg, const float* __restrict__ WhhE, float* __restrict__ hmean,
    const float* __restrict__ Wo, __hip_bfloat16* __restrict__ Bhi, __hip_bfloat16* __restrict__ Blo,
    const int* __restrict__ esrc, const int* __restrict__ edst, const int* __restrict__ nids,
    const float* __restrict__ emb,
    float* __restrict__ deg, float* __restrict__ dinv, float* __restrict__ s1,
    float* __restrict__ s2, float* __restrict__ cc, float* __restrict__ ee,
    float* __restrict__ csum, float* __restrict__ gvec,
    const float* __restrict__ W1, const float* __restrict__ b1,
    const float* __restrict__ W2, const float* __restrict__ b2, float* __restrict__ mvec,
    int* bar)
{
  __shared__ __align__(16) char shraw[131072];   // 128KB -> 1 block/CU (isolation)
  const int bid = blockIdx.x, tid = threadIdx.x;

  if (bid < 8) {
    // ---------------- encoder scan role (round-4 proven body) -----------------
    float* h_s   = (float*)shraw;
    float* act_s = ((float*)shraw) + 128;
    const int b = bid;

    const f32x4* Wrow = (const f32x4*)(WhhE + (size_t)tid*HH);
    f32x4 w[32];
    #pragma unroll
    for (int k=0;k<32;k++) w[k] = Wrow[k];
    #pragma unroll
    for (int k=0;k<32;k++) asm volatile("" : "+v"(w[k]));

    const float* xgrow = xg + (size_t)b*SS*512;
    float xv = xgrow[tid];
    if (tid < 128) h_s[tid] = 0.f;
    float cstate = 0.f, hsum = 0.f;
    __syncthreads();

    for (int t=0;t<SS;t++) {
      int tn = (t < SS-1) ? (t+1) : t;
      float nxv = xgrow[(size_t)tn*512 + tid];
      float a0=0.f,a1=0.f,a2=0.f,a3=0.f;
      #pragma unroll
      for (int k=0;k<32;k++) {
        f32x4 hv = *(const f32x4*)&h_s[k*4];
        a0 += w[k].x*hv.x; a1 += w[k].y*hv.y;
        a2 += w[k].z*hv.z; a3 += w[k].w*hv.w;
      }
      float s = (a0+a1)+(a2+a3) + xv;
      int gid = tid >> 7;
      float act = (gid==2) ? tanhf(s) : 1.0f/(1.0f+expf(-s));
      act_s[tid] = act;
      __syncthreads();
      if (tid < 128) {
        float i_ = act_s[tid], f_ = act_s[128+tid], g_ = act_s[256+tid], o_ = act_s[384+tid];
        cstate = f_*cstate + i_*g_;
        float hh = o_*tanhf(cstate);
        h_s[tid] = hh;
        hsum += hh;
      }
      xv = nxv;
      __syncthreads();
    }
    if (tid < 128) hmean[b*HH + tid] = hsum * (1.0f/512.0f);
  } else {
    // ---------------- worker role: Wo split + graph pipeline ------------------
    const int wbid = bid - 8;
    float* red = (float*)shraw;                  // 512 reduce scratch

    // P0: split Wo -> (bf16 hi, lo), fully nt (32MB read + 16MB write stream)
    for (int i = wbid*512 + tid; i < VV*HH/4; i += NWORK*512) {
      f32x4 v = __builtin_nontemporal_load((const f32x4*)&Wo[i*4]);
      float vv[4] = {v.x, v.y, v.z, v.w};
      #pragma unroll
      for (int k=0;k<4;k++) {
        __hip_bfloat16 h = __float2bfloat16(vv[k]);
        float rem = vv[k] - __bfloat162float(h);
        __hip_bfloat16 l = __float2bfloat16(rem);
        __builtin_nontemporal_store(*(unsigned short*)&h, (unsigned short*)&Bhi[i*4+k]);
        __builtin_nontemporal_store(*(unsigned short*)&l, (unsigned short*)&Blo[i*4+k]);
      }
    }
    workers_barrier(bar, tid);
    // P1: degree (edge list read nt)
    for (int i = wbid*512 + tid; i < NEDGE; i += NWORK*512)
      atomicAdd(&deg[ntload_i(&edst[i])], 1.0f);
    workers_barrier(bar, tid);
    // P2: dinv
    for (int n = wbid*512 + tid; n < NNODE; n += NWORK*512)
      dinv[n] = 1.0f / sqrtf(ntload_f(&deg[n]) + 1.0f);
    workers_barrier(bar, tid);
    // P3: s1
    for (int i = wbid*512 + tid; i < NEDGE; i += NWORK*512)
      atomicAdd(&s1[ntload_i(&esrc[i])], ntload_f(&dinv[ntload_i(&edst[i])]));
    workers_barrier(bar, tid);
    // P4: cc + csum
    {
      float lsum = 0.f;
      for (int n = wbid*512 + tid; n < NNODE; n += NWORK*512) {
        float d = ntload_f(&dinv[n]); float v = d*ntload_f(&s1[n]) + d*d;
        cc[n] = v; lsum += v;
      }
      red[tid] = lsum; __syncthreads();
      for (int sfl=256; sfl>0; sfl>>=1) { if (tid < sfl) red[tid] += red[tid+sfl]; __syncthreads(); }
      if (tid==0) atomicAdd(csum, red[0]);
    }
    workers_barrier(bar, tid);
    // P5: s2
    for (int i = wbid*512 + tid; i < NEDGE; i += NWORK*512) {
      int d = ntload_i(&edst[i]);
      atomicAdd(&s2[ntload_i(&esrc[i])], ntload_f(&cc[d])*ntload_f(&dinv[d]));
    }
    workers_barrier(bar, tid);
    // P6: ee
    for (int n = wbid*512 + tid; n < NNODE; n += NWORK*512) {
      float d = ntload_f(&dinv[n]);
      ee[n] = d*ntload_f(&s2[n]) + ntload_f(&cc[n])*d*d;
    }
    workers_barrier(bar, tid);
    // P7: gvec[j] = sum_n ee[n]*emb[nids[n]][j]  (emb gather nt: 25.6MB)
    {
      int j = tid & 127, sub = tid >> 7;         // 4 n-lanes per block
      float acc = 0.f;
      for (int n = wbid*4 + sub; n < NNODE; n += NWORK*4)
        acc += ntload_f(&ee[n]) * ntload_f(&emb[(size_t)ntload_i(&nids[n])*HH + j]);
      red[tid] = acc; __syncthreads();
      if (tid < 128) atomicAdd(&gvec[j], red[tid] + red[tid+128] + red[tid+256] + red[tid+384]);
    }
    workers_barrier(bar, tid);
    // P8: graph final (block 0, full-block barriers)
    if (wbid == 0) {
      float* gs = (float*)shraw;
      float* v1 = gs + 128;
      if (tid < 128) gs[tid] = gvec[tid];
      __syncthreads();
      if (tid < 128) {
        float a = 0.f;
        for (int k=0;k<128;k++) a += gs[k]*W1[tid*128+k];
        v1[tid] = a + csum[0]*b1[tid];
      }
      __syncthreads();
      if (tid < 128) {
        float a2 = 0.f;
        for (int k=0;k<128;k++) a2 += v1[k]*W2[tid*128+k];
        mvec[tid] = a2 * (1.0f/(float)NNODE) + b2[tid];
      }
    }
  }
}

// ---------------- FUSED decoder scan + PERSISTENT-owner output GEMM ----------
// Blocks 0-7: in-kernel fusion (comb->fused->xv, bit-identical to the old
// fusion_kernel) then decoder scan, publish prog[b*32] every 64 steps.
// Blocks 8..247: persistent owners; B panel staged once in LDS; A-fragments
// read NON-TEMPORAL so 240 owners' bursts don't evict the scans' W_hh from L2
// (round-15/17 interference mechanism, now fixed on the read side too).
__global__ __launch_bounds__(512) void dec_gemm_kernel(
    const float* __restrict__ hmean, const float* __restrict__ mvec,
    const float* __restrict__ Wf, const float* __restrict__ bfv,
    const float* __restrict__ Wihd, const float* __restrict__ bd,
    const float* __restrict__ Whh,
    __hip_bfloat16* __restrict__ ahi, __hip_bfloat16* __restrict__ alo,
    const __hip_bfloat16* __restrict__ Bhi, const __hip_bfloat16* __restrict__ Blo,
    const float* __restrict__ bo, float* __restrict__ out, int* __restrict__ prog)
{
  __shared__ __align__(16) char shraw[131072];   // 128KB -> 1 block/CU
  const int bid = blockIdx.x, tid = threadIdx.x;

  if (bid < 8) {
    // ---------------- decoder scan role (round-4 body + inline fusion) --------
    float* h_s   = (float*)shraw;
    float* act_s = ((float*)shraw) + 128;        // also reused as comb[256]
    float* fus   = (float*)(shraw + 4096);       // 128 floats
    const int b = bid;

    const f32x4* Wrow = (const f32x4*)(Whh + (size_t)tid*HH);
    f32x4 w[32];
    #pragma unroll
    for (int k=0;k<32;k++) w[k] = Wrow[k];
    #pragma unroll
    for (int k=0;k<32;k++) asm volatile("" : "+v"(w[k]));

    // inline fusion: comb = [hmean[b], mvec]; fused = comb@Wf^T+bf;
    // xv = fused@Wihd_row(tid) + bd[tid]   (same loop order as fusion_kernel)
    float* comb = act_s;
    if (tid < 128) comb[tid] = hmean[b*128 + tid];
    else if (tid < 256) comb[tid] = mvec[tid - 128];
    __syncthreads();
    if (tid < 128) {
      float a = 0.f;
      for (int k=0;k<256;k++) a += comb[k]*Wf[tid*256+k];
      fus[tid] = a + bfv[tid];
    }
    __syncthreads();
    float xv;
    {
      float a = 0.f;
      for (int k=0;k<128;k++) a += fus[k]*Wihd[tid*128+k];
      xv = a + bd[tid];
    }
    __syncthreads();                             // before reusing act_s
    if (tid < 128) h_s[tid] = 0.f;
    float cstate = 0.f;
    __syncthreads();

    for (int t=0;t<SS;t++) {
      float a0=0.f,a1=0.f,a2=0.f,a3=0.f;
      #pragma unroll
      for (int k=0;k<32;k++) {
        f32x4 hv = *(const f32x4*)&h_s[k*4];
        a0 += w[k].x*hv.x; a1 += w[k].y*hv.y;
        a2 += w[k].z*hv.z; a3 += w[k].w*hv.w;
      }
      float s = (a0+a1)+(a2+a3) + xv;
      int gid = tid >> 7;
      float act = (gid==2) ? tanhf(s) : 1.0f/(1.0f+expf(-s));
      act_s[tid] = act;
      __syncthreads();
      if (tid < 128) {
        float i_ = act_s[tid], f_ = act_s[128+tid], g_ = act_s[256+tid], o_ = act_s[384+tid];
        cstate = f_*cstate + i_*g_;
        float hh = o_*tanhf(cstate);
        h_s[tid] = hh;
        size_t row = (size_t)b*SS + t;
        __hip_bfloat16 hi = __float2bfloat16(hh);
        float rem = hh - __bfloat162float(hi);
        __hip_bfloat16 lo = __float2bfloat16(rem);
        __builtin_nontemporal_store(*(unsigned short*)&hi, (unsigned short*)&ahi[row*HH + tid]);
        __builtin_nontemporal_store(*(unsigned short*)&lo, (unsigned short*)&alo[row*HH + tid]);
      }
      __syncthreads();
      if ((t & 63) == 63) {                     // publish completed 64-step chunk
        __threadfence();
        __syncthreads();
        if (tid == 0)
          __hip_atomic_store(&prog[b*32], (t >> 6) + 1,
                             __ATOMIC_RELEASE, __HIP_MEMORY_SCOPE_AGENT);
      }
    }
  } else {
    // ---------------- persistent gemm owner ----------------
    short* smem = (short*)shraw;                // hi plane @0, lo plane @64KB
    const int o = bid - 8;                      // 0..239
    int nblk, b0, nb;
    if (o < 230) { nblk = o >> 1; b0 = (o & 1) * 4; nb = 4; }
    else         { nblk = 115 + (o - 230); b0 = 0; nb = 8; }

    // stage B panel once (256 cols x 128 k, hi+lo), inverse-swizzled source
    const short* bsrc[2] = {
      (const short*)Bhi + (size_t)nblk*256*HH,
      (const short*)Blo + (size_t)nblk*256*HH };
    #pragma unroll
    for (int p=0;p<2;p++) {
      #pragma unroll
      for (int it=0; it<8; it++) {
        int off  = it*8192 + tid*16;
        int row  = off >> 8;
        int soff = off ^ ((row & 15) << 4);
        __builtin_amdgcn_global_load_lds(
          (const __attribute__((address_space(1))) void*)((const char*)bsrc[p] + soff),
          (__attribute__((address_space(3))) void*)((char*)smem + p*65536 + off),
          16, 0, 0);
      }
    }
    __syncthreads();

    const int lane = tid & 63;
    const int wid  = tid >> 6;
    const int wm = wid >> 2, wn = wid & 3;      // 2m x 4n waves: 32x64 each
    const int l15 = lane & 15, l4 = lane >> 4;
    const short* Ah = (const short*)ahi;
    const short* Al = (const short*)alo;

    for (int c = 0; c < 8; ++c) {
      for (int bi = 0; bi < nb; ++bi) {
        int b = b0 + bi;
        if (tid == 0) {                         // single-lane, slow poll
          while (__hip_atomic_load(&prog[b*32], __ATOMIC_ACQUIRE,
                                   __HIP_MEMORY_SCOPE_AGENT) <= c)
            __builtin_amdgcn_s_sleep(64);
        }
        __syncthreads();

        const int mbase = b*512 + c*64 + wm*32;
        f32x4 acc[2][4] = {};
        #pragma unroll
        for (int s=0;s<4;s++) {
          s16x8 bh[4], bl[4], ah[2], al[2];
          #pragma unroll
          for (int qn=0;qn<4;qn++) {
            int rb   = wn*64 + qn*16 + l15;
            int offb = (rb*256 + s*64 + l4*16) ^ ((rb & 15) << 4);
            bh[qn] = *(const s16x8*)((const char*)smem + offb);
            bl[qn] = *(const s16x8*)((const char*)smem + 65536 + offb);
          }
          #pragma unroll
          for (int qm=0;qm<2;qm++) {
            int arow = mbase + qm*16 + l15;
            size_t aoff = (size_t)arow*HH + s*32 + l4*8;
            // nt A-reads: do not allocate in L2 (protect scan W_hh)
            ah[qm] = __builtin_nontemporal_load((const s16x8*)(Ah + aoff));
            al[qm] = __builtin_nontemporal_load((const s16x8*)(Al + aoff));
          }
          #pragma unroll
          for (int qm=0;qm<2;qm++) {
            #pragma unroll
            for (int qn=0;qn<4;qn++) {
              acc[qm][qn] = __builtin_amdgcn_mfma_f32_16x16x32_bf16(bh[qn], ah[qm], acc[qm][qn], 0,0,0);
              acc[qm][qn] = __builtin_amdgcn_mfma_f32_16x16x32_bf16(bl[qn], ah[qm], acc[qm][qn], 0,0,0);
              acc[qm][qn] = __builtin_amdgcn_mfma_f32_16x16x32_bf16(bh[qn], al[qm], acc[qm][qn], 0,0,0);
            }
          }
        }
        #pragma unroll
        for (int qm=0;qm<2;qm++) {
          int row = mbase + qm*16 + l15;        // swapped C/D: l15 = M-row
          #pragma unroll
          for (int qn=0;qn<4;qn++) {
            int colb = nblk*256 + wn*64 + qn*16 + l4*4;
            f32x4 bv = *(const f32x4*)&bo[colb];
            f32x4 oo = acc[qm][qn] + bv;
            // nt store: 512MB stream must not evict scan weights from L2
            __builtin_nontemporal_store(oo, (f32x4*)&out[(size_t)row*VV + colb]);
          }
        }
      }
    }
  }
}

// ---------------- launch ----------------
extern "C" void kernel_launch(void* const* d_in, const int* in_sizes, int n_in,
                              void* d_out, int out_size, void* d_ws, size_t ws_size,
                              hipStream_t stream)
{
  (void)in_sizes; (void)n_in; (void)out_size; (void)ws_size;
  const int*   jin   = (const int*)d_in[0];
  const int*   nids  = (const int*)d_in[1];
  const int*   esrc  = (const int*)d_in[2];
  const int*   edst  = esrc + NEDGE;
  const float* emb   = (const float*)d_in[3];
  const float* WihE  = (const float*)d_in[4];
  const float* WhhE  = (const float*)d_in[5];
  const float* bE    = (const float*)d_in[6];
  const float* W1    = (const float*)d_in[7];
  const float* b1    = (const float*)d_in[8];
  const float* W2    = (const float*)d_in[9];
  const float* b2    = (const float*)d_in[10];
  const float* Wf    = (const float*)d_in[11];
  const float* bfv   = (const float*)d_in[12];
  const float* WihD  = (const float*)d_in[13];
  const float* WhhD  = (const float*)d_in[14];
  const float* bD    = (const float*)d_in[15];
  const float* Wo    = (const float*)d_in[16];
  const float* bo    = (const float*)d_in[17];
  float* out = (float*)d_out;

  char* ws = (char*)d_ws;
  size_t off = 0;
  auto alloc = [&](size_t bytes) { size_t o = off; off = (off + bytes + 255) & ~(size_t)255; return o; };

  int*   prog = (int*)(ws + alloc(BB*32*4));       // decoder progress (line/batch)
  int*   bar  = (int*)(ws + alloc(64*4));          // workers barrier cnt/gen
  float* deg  = (float*)(ws + alloc(NNODE*4));
  float* s1   = (float*)(ws + alloc(NNODE*4));
  float* s2   = (float*)(ws + alloc(NNODE*4));
  float* gvec = (float*)(ws + alloc(128*4));
  float* csum = (float*)(ws + alloc(4));
  size_t zero_bytes = off;
  float* dinv = (float*)(ws + alloc(NNODE*4));
  float* cc   = (float*)(ws + alloc(NNODE*4));
  float* ee   = (float*)(ws + alloc(NNODE*4));
  float* mvec = (float*)(ws + alloc(128*4));
  float* hmean= (float*)(ws + alloc(BB*HH*4));
  float* xgenc= (float*)(ws + alloc((size_t)BB*SS*512*4));
  __hip_bfloat16* Ahi = (__hip_bfloat16*)(ws + alloc((size_t)BB*SS*HH*2));
  __hip_bfloat16* Alo = (__hip_bfloat16*)(ws + alloc((size_t)BB*SS*HH*2));
  __hip_bfloat16* Bhi = (__hip_bfloat16*)(ws + alloc((size_t)VV*HH*2));
  __hip_bfloat16* Blo = (__hip_bfloat16*)(ws + alloc((size_t)VV*HH*2));

  hipMemsetAsync(ws, 0, zero_bytes, stream);

  // serial xg production (tiny, ~20us)
  xg_enc_kernel<<<dim3((BB*SS)/8), dim3(256), 0, stream>>>(jin, emb, WihE, bE, xgenc);

  // front: clean enc scan + {Wo split, graph pipeline} on idle CUs
  front_kernel<<<dim3(8 + NWORK), dim3(512), 0, stream>>>(
      xgenc, WhhE, hmean, Wo, Bhi, Blo,
      esrc, edst, nids, emb, deg, dinv, s1, s2, cc, ee, csum, gvec,
      W1, b1, W2, b2, mvec, bar);

  // fused: inline-fusion + decoder scan + persistent-owner GEMM
  dec_gemm_kernel<<<dim3(8 + NWORK), dim3(512), 0, stream>>>(
      hmean, mvec, Wf, bfv, WihD, bD, WhhD,
      Ahi, Alo, Bhi, Blo, bo, out, prog);
}

// Round 19
// 1129.258 us; speedup vs baseline: 1.1366x; 1.1366x over previous
//
#include <hip/hip_runtime.h>
#include <hip/hip_bf16.h>
#include <stdint.h>

#define VV 32000
#define HH 128
#define BB 8
#define SS 512
#define NNODE 50000
#define NEDGE 600000
#define NWORK 240          // worker blocks in front kernel (248 total <= 256 CUs)

typedef __attribute__((ext_vector_type(8))) short s16x8;
typedef __attribute__((ext_vector_type(4))) float f32x4;

__device__ __forceinline__ void workers_barrier(int* bar, int tid) {
  __syncthreads();
  if (tid == 0) {
    int g = __hip_atomic_load(&bar[32], __ATOMIC_ACQUIRE, __HIP_MEMORY_SCOPE_AGENT);
    int old = __hip_atomic_fetch_add(&bar[0], 1, __ATOMIC_ACQ_REL, __HIP_MEMORY_SCOPE_AGENT);
    if (old == NWORK-1) {
      __hip_atomic_store(&bar[0], 0, __ATOMIC_RELAXED, __HIP_MEMORY_SCOPE_AGENT);
      __hip_atomic_store(&bar[32], g+1, __ATOMIC_RELEASE, __HIP_MEMORY_SCOPE_AGENT);
    } else {
      while (__hip_atomic_load(&bar[32], __ATOMIC_ACQUIRE, __HIP_MEMORY_SCOPE_AGENT) == g)
        __builtin_amdgcn_s_sleep(32);
    }
  }
  __syncthreads();
}

__device__ __forceinline__ int ntload_i(const int* p) {
  return __builtin_nontemporal_load(p);
}
__device__ __forceinline__ float ntload_f(const float* p) {
  return __builtin_nontemporal_load(p);
}

// ---------------- embedding gather + encoder input-gate GEMM (serial, ~20us) ----
__global__ __launch_bounds__(256) void xg_enc_kernel(
    const int* __restrict__ jin, const float* __restrict__ emb,
    const float* __restrict__ Wih, const float* __restrict__ bvec,
    float* __restrict__ xg)
{
  __shared__ __align__(16) float arow[8][128];
  const int tid = threadIdx.x, blk = blockIdx.x;
  {
    int r = tid >> 5, c = (tid & 31) << 2;
    int tok = jin[blk*8 + r];
    *(float4*)&arow[r][c] = *(const float4*)&emb[(size_t)tok*HH + c];
  }
  __syncthreads();
  const int g0 = tid * 2;
  const float* w0 = Wih + (size_t)g0*HH;
  const float* w1 = w0 + HH;
  float acc0[8], acc1[8];
  #pragma unroll
  for (int r=0;r<8;r++){ acc0[r]=0.f; acc1[r]=0.f; }
  for (int k=0;k<HH;k+=4) {
    float4 wa = *(const float4*)&w0[k];
    float4 wb = *(const float4*)&w1[k];
    #pragma unroll
    for (int r=0;r<8;r++) {
      float4 av = *(const float4*)&arow[r][k];
      acc0[r] += av.x*wa.x + av.y*wa.y + av.z*wa.z + av.w*wa.w;
      acc1[r] += av.x*wb.x + av.y*wb.y + av.z*wb.z + av.w*wb.w;
    }
  }
  float bb0 = bvec[g0], bb1 = bvec[g0+1];
  #pragma unroll
  for (int r=0;r<8;r++) {
    size_t row = (size_t)blk*8 + r;
    xg[row*512 + g0]     = acc0[r] + bb0;
    xg[row*512 + g0 + 1] = acc1[r] + bb1;
  }
}

// ---------------- FRONT: clean enc scan (blocks 0-7) + workers (split + graph) ----
__global__ __launch_bounds__(512) void front_kernel(
    const float* __restrict__ xg, const float* __restrict__ WhhE, float* __restrict__ hmean,
    const float* __restrict__ Wo, __hip_bfloat16* __restrict__ Bhi, __hip_bfloat16* __restrict__ Blo,
    const int* __restrict__ esrc, const int* __restrict__ edst, const int* __restrict__ nids,
    const float* __restrict__ emb,
    float* __restrict__ deg, float* __restrict__ dinv, float* __restrict__ s1,
    float* __restrict__ s2, float* __restrict__ cc, float* __restrict__ ee,
    float* __restrict__ csum, float* __restrict__ gvec,
    const float* __restrict__ W1, const float* __restrict__ b1,
    const float* __restrict__ W2, const float* __restrict__ b2, float* __restrict__ mvec,
    int* bar)
{
  __shared__ __align__(16) char shraw[131072];   // 128KB -> 1 block/CU (isolation)
  const int bid = blockIdx.x, tid = threadIdx.x;

  if (bid < 8) {
    // ---------------- encoder scan role (round-4 proven body) -----------------
    float* h_s   = (float*)shraw;
    float* act_s = ((float*)shraw) + 128;
    const int b = bid;

    const f32x4* Wrow = (const f32x4*)(WhhE + (size_t)tid*HH);
    f32x4 w[32];
    #pragma unroll
    for (int k=0;k<32;k++) w[k] = Wrow[k];
    #pragma unroll
    for (int k=0;k<32;k++) asm volatile("" : "+v"(w[k]));

    const float* xgrow = xg + (size_t)b*SS*512;
    float xv = xgrow[tid];
    if (tid < 128) h_s[tid] = 0.f;
    float cstate = 0.f, hsum = 0.f;
    __syncthreads();

    for (int t=0;t<SS;t++) {
      int tn = (t < SS-1) ? (t+1) : t;
      float nxv = xgrow[(size_t)tn*512 + tid];
      float a0=0.f,a1=0.f,a2=0.f,a3=0.f;
      #pragma unroll
      for (int k=0;k<32;k++) {
        f32x4 hv = *(const f32x4*)&h_s[k*4];
        a0 += w[k].x*hv.x; a1 += w[k].y*hv.y;
        a2 += w[k].z*hv.z; a3 += w[k].w*hv.w;
      }
      float s = (a0+a1)+(a2+a3) + xv;
      int gid = tid >> 7;
      float act = (gid==2) ? tanhf(s) : 1.0f/(1.0f+expf(-s));
      act_s[tid] = act;
      __syncthreads();
      if (tid < 128) {
        float i_ = act_s[tid], f_ = act_s[128+tid], g_ = act_s[256+tid], o_ = act_s[384+tid];
        cstate = f_*cstate + i_*g_;
        float hh = o_*tanhf(cstate);
        h_s[tid] = hh;
        hsum += hh;
      }
      xv = nxv;
      __syncthreads();
    }
    if (tid < 128) hmean[b*HH + tid] = hsum * (1.0f/512.0f);
  } else {
    // ---------------- worker role: Wo split + graph pipeline ------------------
    const int wbid = bid - 8;
    float* red = (float*)shraw;                  // 512 reduce scratch

    // P0: split Wo -> (bf16 hi, lo), fully nt (32MB read + 16MB write stream)
    for (int i = wbid*512 + tid; i < VV*HH/4; i += NWORK*512) {
      f32x4 v = __builtin_nontemporal_load((const f32x4*)&Wo[i*4]);
      float vv[4] = {v.x, v.y, v.z, v.w};
      #pragma unroll
      for (int k=0;k<4;k++) {
        __hip_bfloat16 h = __float2bfloat16(vv[k]);
        float rem = vv[k] - __bfloat162float(h);
        __hip_bfloat16 l = __float2bfloat16(rem);
        __builtin_nontemporal_store(*(unsigned short*)&h, (unsigned short*)&Bhi[i*4+k]);
        __builtin_nontemporal_store(*(unsigned short*)&l, (unsigned short*)&Blo[i*4+k]);
      }
    }
    workers_barrier(bar, tid);
    // P1: degree (edge list read nt)
    for (int i = wbid*512 + tid; i < NEDGE; i += NWORK*512)
      atomicAdd(&deg[ntload_i(&edst[i])], 1.0f);
    workers_barrier(bar, tid);
    // P2: dinv
    for (int n = wbid*512 + tid; n < NNODE; n += NWORK*512)
      dinv[n] = 1.0f / sqrtf(ntload_f(&deg[n]) + 1.0f);
    workers_barrier(bar, tid);
    // P3: s1  (dinv gather NORMAL: 12x reuse across edges wants L2)
    for (int i = wbid*512 + tid; i < NEDGE; i += NWORK*512)
      atomicAdd(&s1[ntload_i(&esrc[i])], dinv[ntload_i(&edst[i])]);
    workers_barrier(bar, tid);
    // P4: cc + csum
    {
      float lsum = 0.f;
      for (int n = wbid*512 + tid; n < NNODE; n += NWORK*512) {
        float d = ntload_f(&dinv[n]); float v = d*ntload_f(&s1[n]) + d*d;
        cc[n] = v; lsum += v;
      }
      red[tid] = lsum; __syncthreads();
      for (int sfl=256; sfl>0; sfl>>=1) { if (tid < sfl) red[tid] += red[tid+sfl]; __syncthreads(); }
      if (tid==0) atomicAdd(csum, red[0]);
    }
    workers_barrier(bar, tid);
    // P5: s2  (cc/dinv gathers NORMAL: reuse)
    for (int i = wbid*512 + tid; i < NEDGE; i += NWORK*512) {
      int d = ntload_i(&edst[i]);
      atomicAdd(&s2[ntload_i(&esrc[i])], cc[d]*dinv[d]);
    }
    workers_barrier(bar, tid);
    // P6: ee
    for (int n = wbid*512 + tid; n < NNODE; n += NWORK*512) {
      float d = ntload_f(&dinv[n]);
      ee[n] = d*ntload_f(&s2[n]) + ntload_f(&cc[n])*d*d;
    }
    workers_barrier(bar, tid);
    // P7: gvec[j] = sum_n ee[n]*emb[nids[n]][j]  (emb rows single-pass -> nt)
    {
      int j = tid & 127, sub = tid >> 7;         // 4 n-lanes per block
      float acc = 0.f;
      for (int n = wbid*4 + sub; n < NNODE; n += NWORK*4)
        acc += ntload_f(&ee[n]) * ntload_f(&emb[(size_t)ntload_i(&nids[n])*HH + j]);
      red[tid] = acc; __syncthreads();
      if (tid < 128) atomicAdd(&gvec[j], red[tid] + red[tid+128] + red[tid+256] + red[tid+384]);
    }
    workers_barrier(bar, tid);
    // P8: graph final (block 0, full-block barriers)
    if (wbid == 0) {
      float* gs = (float*)shraw;
      float* v1 = gs + 128;
      if (tid < 128) gs[tid] = gvec[tid];
      __syncthreads();
      if (tid < 128) {
        float a = 0.f;
        for (int k=0;k<128;k++) a += gs[k]*W1[tid*128+k];
        v1[tid] = a + csum[0]*b1[tid];
      }
      __syncthreads();
      if (tid < 128) {
        float a2 = 0.f;
        for (int k=0;k<128;k++) a2 += v1[k]*W2[tid*128+k];
        mvec[tid] = a2 * (1.0f/(float)NNODE) + b2[tid];
      }
    }
  }
}

// ---------------- FUSED decoder scan + PERSISTENT-owner output GEMM ----------
// Blocks 0-7: inline fusion (bit-identical) + decoder scan, publish prog[b*32]
// every 64 steps (nt stores for ahi/alo). Blocks 8..247: persistent owners;
// B panel staged once in LDS; A-fragments NORMAL loads (high reuse across
// owners -> MUST allocate in L2; round-18's nt-A was a 190us regression);
// out writes nt (write-once stream).
__global__ __launch_bounds__(512) void dec_gemm_kernel(
    const float* __restrict__ hmean, const float* __restrict__ mvec,
    const float* __restrict__ Wf, const float* __restrict__ bfv,
    const float* __restrict__ Wihd, const float* __restrict__ bd,
    const float* __restrict__ Whh,
    __hip_bfloat16* __restrict__ ahi, __hip_bfloat16* __restrict__ alo,
    const __hip_bfloat16* __restrict__ Bhi, const __hip_bfloat16* __restrict__ Blo,
    const float* __restrict__ bo, float* __restrict__ out, int* __restrict__ prog)
{
  __shared__ __align__(16) char shraw[131072];   // 128KB -> 1 block/CU
  const int bid = blockIdx.x, tid = threadIdx.x;

  if (bid < 8) {
    // ---------------- decoder scan role (round-4 body + inline fusion) --------
    float* h_s   = (float*)shraw;
    float* act_s = ((float*)shraw) + 128;        // also reused as comb[256]
    float* fus   = (float*)(shraw + 4096);       // 128 floats
    const int b = bid;

    const f32x4* Wrow = (const f32x4*)(Whh + (size_t)tid*HH);
    f32x4 w[32];
    #pragma unroll
    for (int k=0;k<32;k++) w[k] = Wrow[k];
    #pragma unroll
    for (int k=0;k<32;k++) asm volatile("" : "+v"(w[k]));

    // inline fusion: comb = [hmean[b], mvec]; fused = comb@Wf^T+bf;
    // xv = fused@Wihd_row(tid) + bd[tid]   (same loop order as fusion_kernel)
    float* comb = act_s;
    if (tid < 128) comb[tid] = hmean[b*128 + tid];
    else if (tid < 256) comb[tid] = mvec[tid - 128];
    __syncthreads();
    if (tid < 128) {
      float a = 0.f;
      for (int k=0;k<256;k++) a += comb[k]*Wf[tid*256+k];
      fus[tid] = a + bfv[tid];
    }
    __syncthreads();
    float xv;
    {
      float a = 0.f;
      for (int k=0;k<128;k++) a += fus[k]*Wihd[tid*128+k];
      xv = a + bd[tid];
    }
    __syncthreads();                             // before reusing act_s
    if (tid < 128) h_s[tid] = 0.f;
    float cstate = 0.f;
    __syncthreads();

    for (int t=0;t<SS;t++) {
      float a0=0.f,a1=0.f,a2=0.f,a3=0.f;
      #pragma unroll
      for (int k=0;k<32;k++) {
        f32x4 hv = *(const f32x4*)&h_s[k*4];
        a0 += w[k].x*hv.x; a1 += w[k].y*hv.y;
        a2 += w[k].z*hv.z; a3 += w[k].w*hv.w;
      }
      float s = (a0+a1)+(a2+a3) + xv;
      int gid = tid >> 7;
      float act = (gid==2) ? tanhf(s) : 1.0f/(1.0f+expf(-s));
      act_s[tid] = act;
      __syncthreads();
      if (tid < 128) {
        float i_ = act_s[tid], f_ = act_s[128+tid], g_ = act_s[256+tid], o_ = act_s[384+tid];
        cstate = f_*cstate + i_*g_;
        float hh = o_*tanhf(cstate);
        h_s[tid] = hh;
        size_t row = (size_t)b*SS + t;
        __hip_bfloat16 hi = __float2bfloat16(hh);
        float rem = hh - __bfloat162float(hi);
        __hip_bfloat16 lo = __float2bfloat16(rem);
        __builtin_nontemporal_store(*(unsigned short*)&hi, (unsigned short*)&ahi[row*HH + tid]);
        __builtin_nontemporal_store(*(unsigned short*)&lo, (unsigned short*)&alo[row*HH + tid]);
      }
      __syncthreads();
      if ((t & 63) == 63) {                     // publish completed 64-step chunk
        __threadfence();
        __syncthreads();
        if (tid == 0)
          __hip_atomic_store(&prog[b*32], (t >> 6) + 1,
                             __ATOMIC_RELEASE, __HIP_MEMORY_SCOPE_AGENT);
      }
    }
  } else {
    // ---------------- persistent gemm owner ----------------
    short* smem = (short*)shraw;                // hi plane @0, lo plane @64KB
    const int o = bid - 8;                      // 0..239
    int nblk, b0, nb;
    if (o < 230) { nblk = o >> 1; b0 = (o & 1) * 4; nb = 4; }
    else         { nblk = 115 + (o - 230); b0 = 0; nb = 8; }

    // stage B panel once (256 cols x 128 k, hi+lo), inverse-swizzled source
    const short* bsrc[2] = {
      (const short*)Bhi + (size_t)nblk*256*HH,
      (const short*)Blo + (size_t)nblk*256*HH };
    #pragma unroll
    for (int p=0;p<2;p++) {
      #pragma unroll
      for (int it=0; it<8; it++) {
        int off  = it*8192 + tid*16;
        int row  = off >> 8;
        int soff = off ^ ((row & 15) << 4);
        __builtin_amdgcn_global_load_lds(
          (const __attribute__((address_space(1))) void*)((const char*)bsrc[p] + soff),
          (__attribute__((address_space(3))) void*)((char*)smem + p*65536 + off),
          16, 0, 0);
      }
    }
    __syncthreads();

    const int lane = tid & 63;
    const int wid  = tid >> 6;
    const int wm = wid >> 2, wn = wid & 3;      // 2m x 4n waves: 32x64 each
    const int l15 = lane & 15, l4 = lane >> 4;
    const short* Ah = (const short*)ahi;
    const short* Al = (const short*)alo;

    for (int c = 0; c < 8; ++c) {
      for (int bi = 0; bi < nb; ++bi) {
        int b = b0 + bi;
        if (tid == 0) {                         // single-lane, slow poll
          while (__hip_atomic_load(&prog[b*32], __ATOMIC_ACQUIRE,
                                   __HIP_MEMORY_SCOPE_AGENT) <= c)
            __builtin_amdgcn_s_sleep(64);
        }
        __syncthreads();

        const int mbase = b*512 + c*64 + wm*32;
        f32x4 acc[2][4] = {};
        #pragma unroll
        for (int s=0;s<4;s++) {
          s16x8 bh[4], bl[4], ah[2], al[2];
          #pragma unroll
          for (int qn=0;qn<4;qn++) {
            int rb   = wn*64 + qn*16 + l15;
            int offb = (rb*256 + s*64 + l4*16) ^ ((rb & 15) << 4);
            bh[qn] = *(const s16x8*)((const char*)smem + offb);
            bl[qn] = *(const s16x8*)((const char*)smem + 65536 + offb);
          }
          #pragma unroll
          for (int qm=0;qm<2;qm++) {
            int arow = mbase + qm*16 + l15;
            size_t aoff = (size_t)arow*HH + s*32 + l4*8;
            ah[qm] = *(const s16x8*)(Ah + aoff);    // NORMAL loads: A reuse wants L2
            al[qm] = *(const s16x8*)(Al + aoff);
          }
          #pragma unroll
          for (int qm=0;qm<2;qm++) {
            #pragma unroll
            for (int qn=0;qn<4;qn++) {
              acc[qm][qn] = __builtin_amdgcn_mfma_f32_16x16x32_bf16(bh[qn], ah[qm], acc[qm][qn], 0,0,0);
              acc[qm][qn] = __builtin_amdgcn_mfma_f32_16x16x32_bf16(bl[qn], ah[qm], acc[qm][qn], 0,0,0);
              acc[qm][qn] = __builtin_amdgcn_mfma_f32_16x16x32_bf16(bh[qn], al[qm], acc[qm][qn], 0,0,0);
            }
          }
        }
        #pragma unroll
        for (int qm=0;qm<2;qm++) {
          int row = mbase + qm*16 + l15;        // swapped C/D: l15 = M-row
          #pragma unroll
          for (int qn=0;qn<4;qn++) {
            int colb = nblk*256 + wn*64 + qn*16 + l4*4;
            f32x4 bv = *(const f32x4*)&bo[colb];
            f32x4 oo = acc[qm][qn] + bv;
            // nt store: 512MB stream must not evict scan weights from L2
            __builtin_nontemporal_store(oo, (f32x4*)&out[(size_t)row*VV + colb]);
          }
        }
      }
    }
  }
}

// ---------------- launch ----------------
extern "C" void kernel_launch(void* const* d_in, const int* in_sizes, int n_in,
                              void* d_out, int out_size, void* d_ws, size_t ws_size,
                              hipStream_t stream)
{
  (void)in_sizes; (void)n_in; (void)out_size; (void)ws_size;
  const int*   jin   = (const int*)d_in[0];
  const int*   nids  = (const int*)d_in[1];
  const int*   esrc  = (const int*)d_in[2];
  const int*   edst  = esrc + NEDGE;
  const float* emb   = (const float*)d_in[3];
  const float* WihE  = (const float*)d_in[4];
  const float* WhhE  = (const float*)d_in[5];
  const float* bE    = (const float*)d_in[6];
  const float* W1    = (const float*)d_in[7];
  const float* b1    = (const float*)d_in[8];
  const float* W2    = (const float*)d_in[9];
  const float* b2    = (const float*)d_in[10];
  const float* Wf    = (const float*)d_in[11];
  const float* bfv   = (const float*)d_in[12];
  const float* WihD  = (const float*)d_in[13];
  const float* WhhD  = (const float*)d_in[14];
  const float* bD    = (const float*)d_in[15];
  const float* Wo    = (const float*)d_in[16];
  const float* bo    = (const float*)d_in[17];
  float* out = (float*)d_out;

  char* ws = (char*)d_ws;
  size_t off = 0;
  auto alloc = [&](size_t bytes) { size_t o = off; off = (off + bytes + 255) & ~(size_t)255; return o; };

  int*   prog = (int*)(ws + alloc(BB*32*4));       // decoder progress (line/batch)
  int*   bar  = (int*)(ws + alloc(64*4));          // workers barrier cnt/gen
  float* deg  = (float*)(ws + alloc(NNODE*4));
  float* s1   = (float*)(ws + alloc(NNODE*4));
  float* s2   = (float*)(ws + alloc(NNODE*4));
  float* gvec = (float*)(ws + alloc(128*4));
  float* csum = (float*)(ws + alloc(4));
  size_t zero_bytes = off;
  float* dinv = (float*)(ws + alloc(NNODE*4));
  float* cc   = (float*)(ws + alloc(NNODE*4));
  float* ee   = (float*)(ws + alloc(NNODE*4));
  float* mvec = (float*)(ws + alloc(128*4));
  float* hmean= (float*)(ws + alloc(BB*HH*4));
  float* xgenc= (float*)(ws + alloc((size_t)BB*SS*512*4));
  __hip_bfloat16* Ahi = (__hip_bfloat16*)(ws + alloc((size_t)BB*SS*HH*2));
  __hip_bfloat16* Alo = (__hip_bfloat16*)(ws + alloc((size_t)BB*SS*HH*2));
  __hip_bfloat16* Bhi = (__hip_bfloat16*)(ws + alloc((size_t)VV*HH*2));
  __hip_bfloat16* Blo = (__hip_bfloat16*)(ws + alloc((size_t)VV*HH*2));

  hipMemsetAsync(ws, 0, zero_bytes, stream);

  // serial xg production (tiny, ~20us)
  xg_enc_kernel<<<dim3((BB*SS)/8), dim3(256), 0, stream>>>(jin, emb, WihE, bE, xgenc);

  // front: clean enc scan + {Wo split, graph pipeline} on idle CUs
  front_kernel<<<dim3(8 + NWORK), dim3(512), 0, stream>>>(
      xgenc, WhhE, hmean, Wo, Bhi, Blo,
      esrc, edst, nids, emb, deg, dinv, s1, s2, cc, ee, csum, gvec,
      W1, b1, W2, b2, mvec, bar);

  // fused: inline-fusion + decoder scan + persistent-owner GEMM
  dec_gemm_kernel<<<dim3(8 + NWORK), dim3(512), 0, stream>>>(
      hmean, mvec, Wf, bfv, WihD, bD, WhhD,
      Ahi, Alo, Bhi, Blo, bo, out, prog);
}

// Round 20
// 1100.371 us; speedup vs baseline: 1.1664x; 1.0263x over previous
//
#include <hip/hip_runtime.h>
#include <hip/hip_bf16.h>
#include <stdint.h>

#define VV 32000
#define HH 128
#define BB 8
#define SS 512
#define NNODE 50000
#define NEDGE 600000
#define NWORK 240          // worker blocks in front kernel (248 total <= 256 CUs)
#define NOWN 125           // persistent gemm owners (one per 256-col B panel)

typedef __attribute__((ext_vector_type(8))) short s16x8;
typedef __attribute__((ext_vector_type(4))) float f32x4;

__device__ __forceinline__ void workers_barrier(int* bar, int tid) {
  __syncthreads();
  if (tid == 0) {
    int g = __hip_atomic_load(&bar[32], __ATOMIC_ACQUIRE, __HIP_MEMORY_SCOPE_AGENT);
    int old = __hip_atomic_fetch_add(&bar[0], 1, __ATOMIC_ACQ_REL, __HIP_MEMORY_SCOPE_AGENT);
    if (old == NWORK-1) {
      __hip_atomic_store(&bar[0], 0, __ATOMIC_RELAXED, __HIP_MEMORY_SCOPE_AGENT);
      __hip_atomic_store(&bar[32], g+1, __ATOMIC_RELEASE, __HIP_MEMORY_SCOPE_AGENT);
    } else {
      while (__hip_atomic_load(&bar[32], __ATOMIC_ACQUIRE, __HIP_MEMORY_SCOPE_AGENT) == g)
        __builtin_amdgcn_s_sleep(32);
    }
  }
  __syncthreads();
}

__device__ __forceinline__ int ntload_i(const int* p) {
  return __builtin_nontemporal_load(p);
}
__device__ __forceinline__ float ntload_f(const float* p) {
  return __builtin_nontemporal_load(p);
}

// ---------------- embedding gather + encoder input-gate GEMM (serial, ~20us) ----
__global__ __launch_bounds__(256) void xg_enc_kernel(
    const int* __restrict__ jin, const float* __restrict__ emb,
    const float* __restrict__ Wih, const float* __restrict__ bvec,
    float* __restrict__ xg)
{
  __shared__ __align__(16) float arow[8][128];
  const int tid = threadIdx.x, blk = blockIdx.x;
  {
    int r = tid >> 5, c = (tid & 31) << 2;
    int tok = jin[blk*8 + r];
    *(float4*)&arow[r][c] = *(const float4*)&emb[(size_t)tok*HH + c];
  }
  __syncthreads();
  const int g0 = tid * 2;
  const float* w0 = Wih + (size_t)g0*HH;
  const float* w1 = w0 + HH;
  float acc0[8], acc1[8];
  #pragma unroll
  for (int r=0;r<8;r++){ acc0[r]=0.f; acc1[r]=0.f; }
  for (int k=0;k<HH;k+=4) {
    float4 wa = *(const float4*)&w0[k];
    float4 wb = *(const float4*)&w1[k];
    #pragma unroll
    for (int r=0;r<8;r++) {
      float4 av = *(const float4*)&arow[r][k];
      acc0[r] += av.x*wa.x + av.y*wa.y + av.z*wa.z + av.w*wa.w;
      acc1[r] += av.x*wb.x + av.y*wb.y + av.z*wb.z + av.w*wb.w;
    }
  }
  float bb0 = bvec[g0], bb1 = bvec[g0+1];
  #pragma unroll
  for (int r=0;r<8;r++) {
    size_t row = (size_t)blk*8 + r;
    xg[row*512 + g0]     = acc0[r] + bb0;
    xg[row*512 + g0 + 1] = acc1[r] + bb1;
  }
}

// ---------------- FRONT: clean enc scan (blocks 0-7) + workers (split + graph) ----
__global__ __launch_bounds__(512) void front_kernel(
    const float* __restrict__ xg, const float* __restrict__ WhhE, float* __restrict__ hmean,
    const float* __restrict__ Wo, __hip_bfloat16* __restrict__ Bhi, __hip_bfloat16* __restrict__ Blo,
    const int* __restrict__ esrc, const int* __restrict__ edst, const int* __restrict__ nids,
    const float* __restrict__ emb,
    float* __restrict__ deg, float* __restrict__ dinv, float* __restrict__ s1,
    float* __restrict__ s2, float* __restrict__ cc, float* __restrict__ ee,
    float* __restrict__ csum, float* __restrict__ gvec,
    const float* __restrict__ W1, const float* __restrict__ b1,
    const float* __restrict__ W2, const float* __restrict__ b2, float* __restrict__ mvec,
    int* bar)
{
  __shared__ __align__(16) char shraw[131072];   // 128KB -> 1 block/CU (isolation)
  const int bid = blockIdx.x, tid = threadIdx.x;

  if (bid < 8) {
    // ---------------- encoder scan role (round-4 proven body) -----------------
    float* h_s   = (float*)shraw;
    float* act_s = ((float*)shraw) + 128;
    const int b = bid;

    const f32x4* Wrow = (const f32x4*)(WhhE + (size_t)tid*HH);
    f32x4 w[32];
    #pragma unroll
    for (int k=0;k<32;k++) w[k] = Wrow[k];
    #pragma unroll
    for (int k=0;k<32;k++) asm volatile("" : "+v"(w[k]));

    const float* xgrow = xg + (size_t)b*SS*512;
    float xv = xgrow[tid];
    if (tid < 128) h_s[tid] = 0.f;
    float cstate = 0.f, hsum = 0.f;
    __syncthreads();

    for (int t=0;t<SS;t++) {
      int tn = (t < SS-1) ? (t+1) : t;
      float nxv = xgrow[(size_t)tn*512 + tid];
      float a0=0.f,a1=0.f,a2=0.f,a3=0.f;
      #pragma unroll
      for (int k=0;k<32;k++) {
        f32x4 hv = *(const f32x4*)&h_s[k*4];
        a0 += w[k].x*hv.x; a1 += w[k].y*hv.y;
        a2 += w[k].z*hv.z; a3 += w[k].w*hv.w;
      }
      float s = (a0+a1)+(a2+a3) + xv;
      int gid = tid >> 7;
      float act = (gid==2) ? tanhf(s) : 1.0f/(1.0f+expf(-s));
      act_s[tid] = act;
      __syncthreads();
      if (tid < 128) {
        float i_ = act_s[tid], f_ = act_s[128+tid], g_ = act_s[256+tid], o_ = act_s[384+tid];
        cstate = f_*cstate + i_*g_;
        float hh = o_*tanhf(cstate);
        h_s[tid] = hh;
        hsum += hh;
      }
      xv = nxv;
      __syncthreads();
    }
    if (tid < 128) hmean[b*HH + tid] = hsum * (1.0f/512.0f);
  } else {
    // ---------------- worker role: Wo split + graph pipeline ------------------
    const int wbid = bid - 8;
    float* red = (float*)shraw;                  // 512 reduce scratch

    // P0: split Wo -> (bf16 hi, lo), fully nt (32MB read + 16MB write stream)
    for (int i = wbid*512 + tid; i < VV*HH/4; i += NWORK*512) {
      f32x4 v = __builtin_nontemporal_load((const f32x4*)&Wo[i*4]);
      float vv[4] = {v.x, v.y, v.z, v.w};
      #pragma unroll
      for (int k=0;k<4;k++) {
        __hip_bfloat16 h = __float2bfloat16(vv[k]);
        float rem = vv[k] - __bfloat162float(h);
        __hip_bfloat16 l = __float2bfloat16(rem);
        __builtin_nontemporal_store(*(unsigned short*)&h, (unsigned short*)&Bhi[i*4+k]);
        __builtin_nontemporal_store(*(unsigned short*)&l, (unsigned short*)&Blo[i*4+k]);
      }
    }
    workers_barrier(bar, tid);
    // P1: degree (edge list read nt)
    for (int i = wbid*512 + tid; i < NEDGE; i += NWORK*512)
      atomicAdd(&deg[ntload_i(&edst[i])], 1.0f);
    workers_barrier(bar, tid);
    // P2: dinv
    for (int n = wbid*512 + tid; n < NNODE; n += NWORK*512)
      dinv[n] = 1.0f / sqrtf(ntload_f(&deg[n]) + 1.0f);
    workers_barrier(bar, tid);
    // P3: s1  (dinv gather NORMAL: 12x reuse across edges wants L2)
    for (int i = wbid*512 + tid; i < NEDGE; i += NWORK*512)
      atomicAdd(&s1[ntload_i(&esrc[i])], dinv[ntload_i(&edst[i])]);
    workers_barrier(bar, tid);
    // P4: cc + csum
    {
      float lsum = 0.f;
      for (int n = wbid*512 + tid; n < NNODE; n += NWORK*512) {
        float d = ntload_f(&dinv[n]); float v = d*ntload_f(&s1[n]) + d*d;
        cc[n] = v; lsum += v;
      }
      red[tid] = lsum; __syncthreads();
      for (int sfl=256; sfl>0; sfl>>=1) { if (tid < sfl) red[tid] += red[tid+sfl]; __syncthreads(); }
      if (tid==0) atomicAdd(csum, red[0]);
    }
    workers_barrier(bar, tid);
    // P5: s2  (cc/dinv gathers NORMAL: reuse)
    for (int i = wbid*512 + tid; i < NEDGE; i += NWORK*512) {
      int d = ntload_i(&edst[i]);
      atomicAdd(&s2[ntload_i(&esrc[i])], cc[d]*dinv[d]);
    }
    workers_barrier(bar, tid);
    // P6: ee
    for (int n = wbid*512 + tid; n < NNODE; n += NWORK*512) {
      float d = ntload_f(&dinv[n]);
      ee[n] = d*ntload_f(&s2[n]) + ntload_f(&cc[n])*d*d;
    }
    workers_barrier(bar, tid);
    // P7: gvec[j] = sum_n ee[n]*emb[nids[n]][j]  (emb rows single-pass -> nt)
    {
      int j = tid & 127, sub = tid >> 7;         // 4 n-lanes per block
      float acc = 0.f;
      for (int n = wbid*4 + sub; n < NNODE; n += NWORK*4)
        acc += ntload_f(&ee[n]) * ntload_f(&emb[(size_t)ntload_i(&nids[n])*HH + j]);
      red[tid] = acc; __syncthreads();
      if (tid < 128) atomicAdd(&gvec[j], red[tid] + red[tid+128] + red[tid+256] + red[tid+384]);
    }
    workers_barrier(bar, tid);
    // P8: graph final (block 0, full-block barriers)
    if (wbid == 0) {
      float* gs = (float*)shraw;
      float* v1 = gs + 128;
      if (tid < 128) gs[tid] = gvec[tid];
      __syncthreads();
      if (tid < 128) {
        float a = 0.f;
        for (int k=0;k<128;k++) a += gs[k]*W1[tid*128+k];
        v1[tid] = a + csum[0]*b1[tid];
      }
      __syncthreads();
      if (tid < 128) {
        float a2 = 0.f;
        for (int k=0;k<128;k++) a2 += v1[k]*W2[tid*128+k];
        mvec[tid] = a2 * (1.0f/(float)NNODE) + b2[tid];
      }
    }
  }
}

// ---------------- FUSED decoder scan + PERSISTENT-owner output GEMM ----------
// Blocks 0-7: inline fusion + decoder scan, publish prog[b*32] every 64 steps.
// Blocks 8..132: 125 persistent owners, ONE 256-col B panel each (staged once
// in 128KB LDS), looping chunks x all-8-batches. Owner concurrency halved vs
// round 19 (240->125) to cut owner<->scan L2/fabric interference; per-publish
// work per owner (~25us) still fits inside the 56us publish interval.
__global__ __launch_bounds__(512) void dec_gemm_kernel(
    const float* __restrict__ hmean, const float* __restrict__ mvec,
    const float* __restrict__ Wf, const float* __restrict__ bfv,
    const float* __restrict__ Wihd, const float* __restrict__ bd,
    const float* __restrict__ Whh,
    __hip_bfloat16* __restrict__ ahi, __hip_bfloat16* __restrict__ alo,
    const __hip_bfloat16* __restrict__ Bhi, const __hip_bfloat16* __restrict__ Blo,
    const float* __restrict__ bo, float* __restrict__ out, int* __restrict__ prog)
{
  __shared__ __align__(16) char shraw[131072];   // 128KB -> 1 block/CU
  const int bid = blockIdx.x, tid = threadIdx.x;

  if (bid < 8) {
    // ---------------- decoder scan role (round-4 body + inline fusion) --------
    float* h_s   = (float*)shraw;
    float* act_s = ((float*)shraw) + 128;        // also reused as comb[256]
    float* fus   = (float*)(shraw + 4096);       // 128 floats
    const int b = bid;

    const f32x4* Wrow = (const f32x4*)(Whh + (size_t)tid*HH);
    f32x4 w[32];
    #pragma unroll
    for (int k=0;k<32;k++) w[k] = Wrow[k];
    #pragma unroll
    for (int k=0;k<32;k++) asm volatile("" : "+v"(w[k]));

    // inline fusion (bit-identical to the old fusion_kernel loop order)
    float* comb = act_s;
    if (tid < 128) comb[tid] = hmean[b*128 + tid];
    else if (tid < 256) comb[tid] = mvec[tid - 128];
    __syncthreads();
    if (tid < 128) {
      float a = 0.f;
      for (int k=0;k<256;k++) a += comb[k]*Wf[tid*256+k];
      fus[tid] = a + bfv[tid];
    }
    __syncthreads();
    float xv;
    {
      float a = 0.f;
      for (int k=0;k<128;k++) a += fus[k]*Wihd[tid*128+k];
      xv = a + bd[tid];
    }
    __syncthreads();                             // before reusing act_s
    if (tid < 128) h_s[tid] = 0.f;
    float cstate = 0.f;
    __syncthreads();

    for (int t=0;t<SS;t++) {
      float a0=0.f,a1=0.f,a2=0.f,a3=0.f;
      #pragma unroll
      for (int k=0;k<32;k++) {
        f32x4 hv = *(const f32x4*)&h_s[k*4];
        a0 += w[k].x*hv.x; a1 += w[k].y*hv.y;
        a2 += w[k].z*hv.z; a3 += w[k].w*hv.w;
      }
      float s = (a0+a1)+(a2+a3) + xv;
      int gid = tid >> 7;
      float act = (gid==2) ? tanhf(s) : 1.0f/(1.0f+expf(-s));
      act_s[tid] = act;
      __syncthreads();
      if (tid < 128) {
        float i_ = act_s[tid], f_ = act_s[128+tid], g_ = act_s[256+tid], o_ = act_s[384+tid];
        cstate = f_*cstate + i_*g_;
        float hh = o_*tanhf(cstate);
        h_s[tid] = hh;
        size_t row = (size_t)b*SS + t;
        __hip_bfloat16 hi = __float2bfloat16(hh);
        float rem = hh - __bfloat162float(hi);
        __hip_bfloat16 lo = __float2bfloat16(rem);
        __builtin_nontemporal_store(*(unsigned short*)&hi, (unsigned short*)&ahi[row*HH + tid]);
        __builtin_nontemporal_store(*(unsigned short*)&lo, (unsigned short*)&alo[row*HH + tid]);
      }
      __syncthreads();
      if ((t & 63) == 63) {                     // publish completed 64-step chunk
        __threadfence();
        __syncthreads();
        if (tid == 0)
          __hip_atomic_store(&prog[b*32], (t >> 6) + 1,
                             __ATOMIC_RELEASE, __HIP_MEMORY_SCOPE_AGENT);
      }
    }
  } else {
    // ---------------- persistent gemm owner: one 256-col panel ----------------
    short* smem = (short*)shraw;                // hi plane @0, lo plane @64KB
    const int nblk = bid - 8;                   // 0..124

    // stage B panel once (256 cols x 128 k, hi+lo), inverse-swizzled source
    const short* bsrc[2] = {
      (const short*)Bhi + (size_t)nblk*256*HH,
      (const short*)Blo + (size_t)nblk*256*HH };
    #pragma unroll
    for (int p=0;p<2;p++) {
      #pragma unroll
      for (int it=0; it<8; it++) {
        int off  = it*8192 + tid*16;
        int row  = off >> 8;
        int soff = off ^ ((row & 15) << 4);
        __builtin_amdgcn_global_load_lds(
          (const __attribute__((address_space(1))) void*)((const char*)bsrc[p] + soff),
          (__attribute__((address_space(3))) void*)((char*)smem + p*65536 + off),
          16, 0, 0);
      }
    }
    __syncthreads();

    const int lane = tid & 63;
    const int wid  = tid >> 6;
    const int wm = wid >> 2, wn = wid & 3;      // 2m x 4n waves: 32x64 each
    const int l15 = lane & 15, l4 = lane >> 4;
    const short* Ah = (const short*)ahi;
    const short* Al = (const short*)alo;

    for (int c = 0; c < 8; ++c) {
      for (int b = 0; b < 8; ++b) {
        if (tid == 0) {                         // single-lane, slow poll
          while (__hip_atomic_load(&prog[b*32], __ATOMIC_ACQUIRE,
                                   __HIP_MEMORY_SCOPE_AGENT) <= c)
            __builtin_amdgcn_s_sleep(64);
        }
        __syncthreads();

        const int mbase = b*512 + c*64 + wm*32;
        f32x4 acc[2][4] = {};
        #pragma unroll
        for (int s=0;s<4;s++) {
          s16x8 bh[4], bl[4], ah[2], al[2];
          #pragma unroll
          for (int qn=0;qn<4;qn++) {
            int rb   = wn*64 + qn*16 + l15;
            int offb = (rb*256 + s*64 + l4*16) ^ ((rb & 15) << 4);
            bh[qn] = *(const s16x8*)((const char*)smem + offb);
            bl[qn] = *(const s16x8*)((const char*)smem + 65536 + offb);
          }
          #pragma unroll
          for (int qm=0;qm<2;qm++) {
            int arow = mbase + qm*16 + l15;
            size_t aoff = (size_t)arow*HH + s*32 + l4*8;
            ah[qm] = *(const s16x8*)(Ah + aoff);    // NORMAL loads: A reuse wants L2
            al[qm] = *(const s16x8*)(Al + aoff);
          }
          #pragma unroll
          for (int qm=0;qm<2;qm++) {
            #pragma unroll
            for (int qn=0;qn<4;qn++) {
              acc[qm][qn] = __builtin_amdgcn_mfma_f32_16x16x32_bf16(bh[qn], ah[qm], acc[qm][qn], 0,0,0);
              acc[qm][qn] = __builtin_amdgcn_mfma_f32_16x16x32_bf16(bl[qn], ah[qm], acc[qm][qn], 0,0,0);
              acc[qm][qn] = __builtin_amdgcn_mfma_f32_16x16x32_bf16(bh[qn], al[qm], acc[qm][qn], 0,0,0);
            }
          }
        }
        #pragma unroll
        for (int qm=0;qm<2;qm++) {
          int row = mbase + qm*16 + l15;        // swapped C/D: l15 = M-row
          #pragma unroll
          for (int qn=0;qn<4;qn++) {
            int colb = nblk*256 + wn*64 + qn*16 + l4*4;
            f32x4 bv = *(const f32x4*)&bo[colb];
            f32x4 oo = acc[qm][qn] + bv;
            // nt store: 512MB stream must not evict scan weights from L2
            __builtin_nontemporal_store(oo, (f32x4*)&out[(size_t)row*VV + colb]);
          }
        }
      }
    }
  }
}

// ---------------- launch ----------------
extern "C" void kernel_launch(void* const* d_in, const int* in_sizes, int n_in,
                              void* d_out, int out_size, void* d_ws, size_t ws_size,
                              hipStream_t stream)
{
  (void)in_sizes; (void)n_in; (void)out_size; (void)ws_size;
  const int*   jin   = (const int*)d_in[0];
  const int*   nids  = (const int*)d_in[1];
  const int*   esrc  = (const int*)d_in[2];
  const int*   edst  = esrc + NEDGE;
  const float* emb   = (const float*)d_in[3];
  const float* WihE  = (const float*)d_in[4];
  const float* WhhE  = (const float*)d_in[5];
  const float* bE    = (const float*)d_in[6];
  const float* W1    = (const float*)d_in[7];
  const float* b1    = (const float*)d_in[8];
  const float* W2    = (const float*)d_in[9];
  const float* b2    = (const float*)d_in[10];
  const float* Wf    = (const float*)d_in[11];
  const float* bfv   = (const float*)d_in[12];
  const float* WihD  = (const float*)d_in[13];
  const float* WhhD  = (const float*)d_in[14];
  const float* bD    = (const float*)d_in[15];
  const float* Wo    = (const float*)d_in[16];
  const float* bo    = (const float*)d_in[17];
  float* out = (float*)d_out;

  char* ws = (char*)d_ws;
  size_t off = 0;
  auto alloc = [&](size_t bytes) { size_t o = off; off = (off + bytes + 255) & ~(size_t)255; return o; };

  int*   prog = (int*)(ws + alloc(BB*32*4));       // decoder progress (line/batch)
  int*   bar  = (int*)(ws + alloc(64*4));          // workers barrier cnt/gen
  float* deg  = (float*)(ws + alloc(NNODE*4));
  float* s1   = (float*)(ws + alloc(NNODE*4));
  float* s2   = (float*)(ws + alloc(NNODE*4));
  float* gvec = (float*)(ws + alloc(128*4));
  float* csum = (float*)(ws + alloc(4));
  size_t zero_bytes = off;
  float* dinv = (float*)(ws + alloc(NNODE*4));
  float* cc   = (float*)(ws + alloc(NNODE*4));
  float* ee   = (float*)(ws + alloc(NNODE*4));
  float* mvec = (float*)(ws + alloc(128*4));
  float* hmean= (float*)(ws + alloc(BB*HH*4));
  float* xgenc= (float*)(ws + alloc((size_t)BB*SS*512*4));
  __hip_bfloat16* Ahi = (__hip_bfloat16*)(ws + alloc((size_t)BB*SS*HH*2));
  __hip_bfloat16* Alo = (__hip_bfloat16*)(ws + alloc((size_t)BB*SS*HH*2));
  __hip_bfloat16* Bhi = (__hip_bfloat16*)(ws + alloc((size_t)VV*HH*2));
  __hip_bfloat16* Blo = (__hip_bfloat16*)(ws + alloc((size_t)VV*HH*2));

  hipMemsetAsync(ws, 0, zero_bytes, stream);

  // serial xg production (tiny, ~20us)
  xg_enc_kernel<<<dim3((BB*SS)/8), dim3(256), 0, stream>>>(jin, emb, WihE, bE, xgenc);

  // front: clean enc scan + {Wo split, graph pipeline} on idle CUs
  front_kernel<<<dim3(8 + NWORK), dim3(512), 0, stream>>>(
      xgenc, WhhE, hmean, Wo, Bhi, Blo,
      esrc, edst, nids, emb, deg, dinv, s1, s2, cc, ee, csum, gvec,
      W1, b1, W2, b2, mvec, bar);

  // fused: inline-fusion + decoder scan + persistent-owner GEMM (125 owners)
  dec_gemm_kernel<<<dim3(8 + NOWN), dim3(512), 0, stream>>>(
      hmean, mvec, Wf, bfv, WihD, bD, WhhD,
      Ahi, Alo, Bhi, Blo, bo, out, prog);
}

// Round 21
// 1099.344 us; speedup vs baseline: 1.1675x; 1.0009x over previous
//
#include <hip/hip_runtime.h>
#include <hip/hip_bf16.h>
#include <stdint.h>

#define VV 32000
#define HH 128
#define BB 8
#define SS 512
#define NNODE 50000
#define NEDGE 600000
#define NWORK 120          // throttled workers (halved intensity under the scan)
#define NOWN 125           // persistent gemm owners (one per 256-col B panel)

typedef __attribute__((ext_vector_type(8))) short s16x8;
typedef __attribute__((ext_vector_type(4))) float f32x4;

__device__ __forceinline__ void workers_barrier(int* bar, int tid) {
  __syncthreads();
  if (tid == 0) {
    int g = __hip_atomic_load(&bar[32], __ATOMIC_ACQUIRE, __HIP_MEMORY_SCOPE_AGENT);
    int old = __hip_atomic_fetch_add(&bar[0], 1, __ATOMIC_ACQ_REL, __HIP_MEMORY_SCOPE_AGENT);
    if (old == NWORK-1) {
      __hip_atomic_store(&bar[0], 0, __ATOMIC_RELAXED, __HIP_MEMORY_SCOPE_AGENT);
      __hip_atomic_store(&bar[32], g+1, __ATOMIC_RELEASE, __HIP_MEMORY_SCOPE_AGENT);
    } else {
      while (__hip_atomic_load(&bar[32], __ATOMIC_ACQUIRE, __HIP_MEMORY_SCOPE_AGENT) == g)
        __builtin_amdgcn_s_sleep(32);
    }
  }
  __syncthreads();
}

__device__ __forceinline__ int ntload_i(const int* p) {
  return __builtin_nontemporal_load(p);
}
__device__ __forceinline__ float ntload_f(const float* p) {
  return __builtin_nontemporal_load(p);
}

// ---------------- embedding gather + encoder input-gate GEMM (serial, ~20us) ----
__global__ __launch_bounds__(256) void xg_enc_kernel(
    const int* __restrict__ jin, const float* __restrict__ emb,
    const float* __restrict__ Wih, const float* __restrict__ bvec,
    float* __restrict__ xg)
{
  __shared__ __align__(16) float arow[8][128];
  const int tid = threadIdx.x, blk = blockIdx.x;
  {
    int r = tid >> 5, c = (tid & 31) << 2;
    int tok = jin[blk*8 + r];
    *(float4*)&arow[r][c] = *(const float4*)&emb[(size_t)tok*HH + c];
  }
  __syncthreads();
  const int g0 = tid * 2;
  const float* w0 = Wih + (size_t)g0*HH;
  const float* w1 = w0 + HH;
  float acc0[8], acc1[8];
  #pragma unroll
  for (int r=0;r<8;r++){ acc0[r]=0.f; acc1[r]=0.f; }
  for (int k=0;k<HH;k+=4) {
    float4 wa = *(const float4*)&w0[k];
    float4 wb = *(const float4*)&w1[k];
    #pragma unroll
    for (int r=0;r<8;r++) {
      float4 av = *(const float4*)&arow[r][k];
      acc0[r] += av.x*wa.x + av.y*wa.y + av.z*wa.z + av.w*wa.w;
      acc1[r] += av.x*wb.x + av.y*wb.y + av.z*wb.z + av.w*wb.w;
    }
  }
  float bb0 = bvec[g0], bb1 = bvec[g0+1];
  #pragma unroll
  for (int r=0;r<8;r++) {
    size_t row = (size_t)blk*8 + r;
    xg[row*512 + g0]     = acc0[r] + bb0;
    xg[row*512 + g0 + 1] = acc1[r] + bb1;
  }
}

// ---------------- FRONT: clean enc scan (blocks 0-7) + workers (split + graph) ----
__global__ __launch_bounds__(512) void front_kernel(
    const float* __restrict__ xg, const float* __restrict__ WhhE, float* __restrict__ hmean,
    const float* __restrict__ Wo, __hip_bfloat16* __restrict__ Bhi, __hip_bfloat16* __restrict__ Blo,
    const int* __restrict__ esrc, const int* __restrict__ edst, const int* __restrict__ nids,
    const float* __restrict__ emb,
    float* __restrict__ deg, float* __restrict__ dinv, float* __restrict__ s1,
    float* __restrict__ s2, float* __restrict__ cc, float* __restrict__ ee,
    float* __restrict__ csum, float* __restrict__ gvec,
    const float* __restrict__ W1, const float* __restrict__ b1,
    const float* __restrict__ W2, const float* __restrict__ b2, float* __restrict__ mvec,
    int* bar)
{
  __shared__ __align__(16) char shraw[131072];   // 128KB -> 1 block/CU (isolation)
  const int bid = blockIdx.x, tid = threadIdx.x;

  if (bid < 8) {
    // ---------------- encoder scan role (round-4 proven body) -----------------
    float* h_s   = (float*)shraw;
    float* act_s = ((float*)shraw) + 128;
    const int b = bid;

    const f32x4* Wrow = (const f32x4*)(WhhE + (size_t)tid*HH);
    f32x4 w[32];
    #pragma unroll
    for (int k=0;k<32;k++) w[k] = Wrow[k];
    #pragma unroll
    for (int k=0;k<32;k++) asm volatile("" : "+v"(w[k]));

    const float* xgrow = xg + (size_t)b*SS*512;
    float xv = xgrow[tid];
    if (tid < 128) h_s[tid] = 0.f;
    float cstate = 0.f, hsum = 0.f;
    __syncthreads();

    for (int t=0;t<SS;t++) {
      int tn = (t < SS-1) ? (t+1) : t;
      float nxv = xgrow[(size_t)tn*512 + tid];
      float a0=0.f,a1=0.f,a2=0.f,a3=0.f;
      #pragma unroll
      for (int k=0;k<32;k++) {
        f32x4 hv = *(const f32x4*)&h_s[k*4];
        a0 += w[k].x*hv.x; a1 += w[k].y*hv.y;
        a2 += w[k].z*hv.z; a3 += w[k].w*hv.w;
      }
      float s = (a0+a1)+(a2+a3) + xv;
      int gid = tid >> 7;
      float act = (gid==2) ? tanhf(s) : 1.0f/(1.0f+expf(-s));
      act_s[tid] = act;
      __syncthreads();
      if (tid < 128) {
        float i_ = act_s[tid], f_ = act_s[128+tid], g_ = act_s[256+tid], o_ = act_s[384+tid];
        cstate = f_*cstate + i_*g_;
        float hh = o_*tanhf(cstate);
        h_s[tid] = hh;
        hsum += hh;
      }
      xv = nxv;
      __syncthreads();
    }
    if (tid < 128) hmean[b*HH + tid] = hsum * (1.0f/512.0f);
  } else {
    // ---------------- worker role: Wo split + graph pipeline ------------------
    const int wbid = bid - 8;
    float* red = (float*)shraw;                  // 512 reduce scratch

    // P0: split Wo -> (bf16 hi, lo), fully nt (32MB read + 16MB write stream)
    for (int i = wbid*512 + tid; i < VV*HH/4; i += NWORK*512) {
      f32x4 v = __builtin_nontemporal_load((const f32x4*)&Wo[i*4]);
      float vv[4] = {v.x, v.y, v.z, v.w};
      #pragma unroll
      for (int k=0;k<4;k++) {
        __hip_bfloat16 h = __float2bfloat16(vv[k]);
        float rem = vv[k] - __bfloat162float(h);
        __hip_bfloat16 l = __float2bfloat16(rem);
        __builtin_nontemporal_store(*(unsigned short*)&h, (unsigned short*)&Bhi[i*4+k]);
        __builtin_nontemporal_store(*(unsigned short*)&l, (unsigned short*)&Blo[i*4+k]);
      }
    }
    workers_barrier(bar, tid);
    // P1: degree (edge list read nt)
    for (int i = wbid*512 + tid; i < NEDGE; i += NWORK*512)
      atomicAdd(&deg[ntload_i(&edst[i])], 1.0f);
    workers_barrier(bar, tid);
    // P2: dinv
    for (int n = wbid*512 + tid; n < NNODE; n += NWORK*512)
      dinv[n] = 1.0f / sqrtf(ntload_f(&deg[n]) + 1.0f);
    workers_barrier(bar, tid);
    // P3: s1  (dinv gather NORMAL: 12x reuse across edges wants L2)
    for (int i = wbid*512 + tid; i < NEDGE; i += NWORK*512)
      atomicAdd(&s1[ntload_i(&esrc[i])], dinv[ntload_i(&edst[i])]);
    workers_barrier(bar, tid);
    // P4: cc + csum
    {
      float lsum = 0.f;
      for (int n = wbid*512 + tid; n < NNODE; n += NWORK*512) {
        float d = ntload_f(&dinv[n]); float v = d*ntload_f(&s1[n]) + d*d;
        cc[n] = v; lsum += v;
      }
      red[tid] = lsum; __syncthreads();
      for (int sfl=256; sfl>0; sfl>>=1) { if (tid < sfl) red[tid] += red[tid+sfl]; __syncthreads(); }
      if (tid==0) atomicAdd(csum, red[0]);
    }
    workers_barrier(bar, tid);
    // P5: s2  (cc/dinv gathers NORMAL: reuse)
    for (int i = wbid*512 + tid; i < NEDGE; i += NWORK*512) {
      int d = ntload_i(&edst[i]);
      atomicAdd(&s2[ntload_i(&esrc[i])], cc[d]*dinv[d]);
    }
    workers_barrier(bar, tid);
    // P6: ee
    for (int n = wbid*512 + tid; n < NNODE; n += NWORK*512) {
      float d = ntload_f(&dinv[n]);
      ee[n] = d*ntload_f(&s2[n]) + ntload_f(&cc[n])*d*d;
    }
    workers_barrier(bar, tid);
    // P7: gvec[j] = sum_n ee[n]*emb[nids[n]][j]  (emb rows single-pass -> nt)
    {
      int j = tid & 127, sub = tid >> 7;         // 4 n-lanes per block
      float acc = 0.f;
      for (int n = wbid*4 + sub; n < NNODE; n += NWORK*4)
        acc += ntload_f(&ee[n]) * ntload_f(&emb[(size_t)ntload_i(&nids[n])*HH + j]);
      red[tid] = acc; __syncthreads();
      if (tid < 128) atomicAdd(&gvec[j], red[tid] + red[tid+128] + red[tid+256] + red[tid+384]);
    }
    workers_barrier(bar, tid);
    // P8: graph final (block 0, full-block barriers)
    if (wbid == 0) {
      float* gs = (float*)shraw;
      float* v1 = gs + 128;
      if (tid < 128) gs[tid] = gvec[tid];
      __syncthreads();
      if (tid < 128) {
        float a = 0.f;
        for (int k=0;k<128;k++) a += gs[k]*W1[tid*128+k];
        v1[tid] = a + csum[0]*b1[tid];
      }
      __syncthreads();
      if (tid < 128) {
        float a2 = 0.f;
        for (int k=0;k<128;k++) a2 += v1[k]*W2[tid*128+k];
        mvec[tid] = a2 * (1.0f/(float)NNODE) + b2[tid];
      }
    }
  }
}

// ---------------- FUSED decoder scan + PERSISTENT-owner output GEMM ----------
// Blocks 0-7: inline fusion + decoder scan, publish prog[b*32] every 32 steps
// (16 chunks -> halved tail). Blocks 8..132: 125 persistent owners, one
// 256-col B panel each (staged once in 128KB LDS), looping 16 chunks x 8
// batches of 32-row tiles. out stores nt EXCEPT the final chunk (scan done ->
// L2 protection moot; normal stores write-combine to full lines, faster drain).
__global__ __launch_bounds__(512) void dec_gemm_kernel(
    const float* __restrict__ hmean, const float* __restrict__ mvec,
    const float* __restrict__ Wf, const float* __restrict__ bfv,
    const float* __restrict__ Wihd, const float* __restrict__ bd,
    const float* __restrict__ Whh,
    __hip_bfloat16* __restrict__ ahi, __hip_bfloat16* __restrict__ alo,
    const __hip_bfloat16* __restrict__ Bhi, const __hip_bfloat16* __restrict__ Blo,
    const float* __restrict__ bo, float* __restrict__ out, int* __restrict__ prog)
{
  __shared__ __align__(16) char shraw[131072];   // 128KB -> 1 block/CU
  const int bid = blockIdx.x, tid = threadIdx.x;

  if (bid < 8) {
    // ---------------- decoder scan role (round-4 body + inline fusion) --------
    float* h_s   = (float*)shraw;
    float* act_s = ((float*)shraw) + 128;        // also reused as comb[256]
    float* fus   = (float*)(shraw + 4096);       // 128 floats
    const int b = bid;

    const f32x4* Wrow = (const f32x4*)(Whh + (size_t)tid*HH);
    f32x4 w[32];
    #pragma unroll
    for (int k=0;k<32;k++) w[k] = Wrow[k];
    #pragma unroll
    for (int k=0;k<32;k++) asm volatile("" : "+v"(w[k]));

    // inline fusion (bit-identical to the old fusion_kernel loop order)
    float* comb = act_s;
    if (tid < 128) comb[tid] = hmean[b*128 + tid];
    else if (tid < 256) comb[tid] = mvec[tid - 128];
    __syncthreads();
    if (tid < 128) {
      float a = 0.f;
      for (int k=0;k<256;k++) a += comb[k]*Wf[tid*256+k];
      fus[tid] = a + bfv[tid];
    }
    __syncthreads();
    float xv;
    {
      float a = 0.f;
      for (int k=0;k<128;k++) a += fus[k]*Wihd[tid*128+k];
      xv = a + bd[tid];
    }
    __syncthreads();                             // before reusing act_s
    if (tid < 128) h_s[tid] = 0.f;
    float cstate = 0.f;
    __syncthreads();

    for (int t=0;t<SS;t++) {
      float a0=0.f,a1=0.f,a2=0.f,a3=0.f;
      #pragma unroll
      for (int k=0;k<32;k++) {
        f32x4 hv = *(const f32x4*)&h_s[k*4];
        a0 += w[k].x*hv.x; a1 += w[k].y*hv.y;
        a2 += w[k].z*hv.z; a3 += w[k].w*hv.w;
      }
      float s = (a0+a1)+(a2+a3) + xv;
      int gid = tid >> 7;
      float act = (gid==2) ? tanhf(s) : 1.0f/(1.0f+expf(-s));
      act_s[tid] = act;
      __syncthreads();
      if (tid < 128) {
        float i_ = act_s[tid], f_ = act_s[128+tid], g_ = act_s[256+tid], o_ = act_s[384+tid];
        cstate = f_*cstate + i_*g_;
        float hh = o_*tanhf(cstate);
        h_s[tid] = hh;
        size_t row = (size_t)b*SS + t;
        __hip_bfloat16 hi = __float2bfloat16(hh);
        float rem = hh - __bfloat162float(hi);
        __hip_bfloat16 lo = __float2bfloat16(rem);
        __builtin_nontemporal_store(*(unsigned short*)&hi, (unsigned short*)&ahi[row*HH + tid]);
        __builtin_nontemporal_store(*(unsigned short*)&lo, (unsigned short*)&alo[row*HH + tid]);
      }
      __syncthreads();
      if ((t & 31) == 31) {                     // publish completed 32-step chunk
        __threadfence();
        __syncthreads();
        if (tid == 0)
          __hip_atomic_store(&prog[b*32], (t >> 5) + 1,
                             __ATOMIC_RELEASE, __HIP_MEMORY_SCOPE_AGENT);
      }
    }
  } else {
    // ---------------- persistent gemm owner: one 256-col panel ----------------
    short* smem = (short*)shraw;                // hi plane @0, lo plane @64KB
    const int nblk = bid - 8;                   // 0..124

    // stage B panel once (256 cols x 128 k, hi+lo), inverse-swizzled source
    const short* bsrc[2] = {
      (const short*)Bhi + (size_t)nblk*256*HH,
      (const short*)Blo + (size_t)nblk*256*HH };
    #pragma unroll
    for (int p=0;p<2;p++) {
      #pragma unroll
      for (int it=0; it<8; it++) {
        int off  = it*8192 + tid*16;
        int row  = off >> 8;
        int soff = off ^ ((row & 15) << 4);
        __builtin_amdgcn_global_load_lds(
          (const __attribute__((address_space(1))) void*)((const char*)bsrc[p] + soff),
          (__attribute__((address_space(3))) void*)((char*)smem + p*65536 + off),
          16, 0, 0);
      }
    }
    __syncthreads();

    const int lane = tid & 63;
    const int wid  = tid >> 6;
    const int wm = wid >> 2, wn = wid & 3;      // 2m x 4n waves: 16x64 each
    const int l15 = lane & 15, l4 = lane >> 4;
    const short* Ah = (const short*)ahi;
    const short* Al = (const short*)alo;

    for (int c = 0; c < 16; ++c) {
      for (int b = 0; b < 8; ++b) {
        if (tid == 0) {                         // single-lane, slow poll
          while (__hip_atomic_load(&prog[b*32], __ATOMIC_ACQUIRE,
                                   __HIP_MEMORY_SCOPE_AGENT) <= c)
            __builtin_amdgcn_s_sleep(64);
        }
        __syncthreads();

        const int mbase = b*512 + c*32 + wm*16;  // 32-row chunk, 16 rows/wave
        f32x4 acc[4] = {};
        #pragma unroll
        for (int s=0;s<4;s++) {
          s16x8 bh[4], bl[4], ah, al;
          #pragma unroll
          for (int qn=0;qn<4;qn++) {
            int rb   = wn*64 + qn*16 + l15;
            int offb = (rb*256 + s*64 + l4*16) ^ ((rb & 15) << 4);
            bh[qn] = *(const s16x8*)((const char*)smem + offb);
            bl[qn] = *(const s16x8*)((const char*)smem + 65536 + offb);
          }
          {
            int arow = mbase + l15;
            size_t aoff = (size_t)arow*HH + s*32 + l4*8;
            ah = *(const s16x8*)(Ah + aoff);    // NORMAL loads: A reuse wants L2
            al = *(const s16x8*)(Al + aoff);
          }
          #pragma unroll
          for (int qn=0;qn<4;qn++) {
            acc[qn] = __builtin_amdgcn_mfma_f32_16x16x32_bf16(bh[qn], ah, acc[qn], 0,0,0);
            acc[qn] = __builtin_amdgcn_mfma_f32_16x16x32_bf16(bl[qn], ah, acc[qn], 0,0,0);
            acc[qn] = __builtin_amdgcn_mfma_f32_16x16x32_bf16(bh[qn], al, acc[qn], 0,0,0);
          }
        }
        {
          int row = mbase + l15;                // swapped C/D: l15 = M-row
          if (c == 15) {                        // scan done: normal stores merge
            #pragma unroll
            for (int qn=0;qn<4;qn++) {
              int colb = nblk*256 + wn*64 + qn*16 + l4*4;
              f32x4 bv = *(const f32x4*)&bo[colb];
              f32x4 oo = acc[qn] + bv;
              *(f32x4*)&out[(size_t)row*VV + colb] = oo;
            }
          } else {                              // nt: protect scan's L2
            #pragma unroll
            for (int qn=0;qn<4;qn++) {
              int colb = nblk*256 + wn*64 + qn*16 + l4*4;
              f32x4 bv = *(const f32x4*)&bo[colb];
              f32x4 oo = acc[qn] + bv;
              __builtin_nontemporal_store(oo, (f32x4*)&out[(size_t)row*VV + colb]);
            }
          }
        }
      }
    }
  }
}

// ---------------- launch ----------------
extern "C" void kernel_launch(void* const* d_in, const int* in_sizes, int n_in,
                              void* d_out, int out_size, void* d_ws, size_t ws_size,
                              hipStream_t stream)
{
  (void)in_sizes; (void)n_in; (void)out_size; (void)ws_size;
  const int*   jin   = (const int*)d_in[0];
  const int*   nids  = (const int*)d_in[1];
  const int*   esrc  = (const int*)d_in[2];
  const int*   edst  = esrc + NEDGE;
  const float* emb   = (const float*)d_in[3];
  const float* WihE  = (const float*)d_in[4];
  const float* WhhE  = (const float*)d_in[5];
  const float* bE    = (const float*)d_in[6];
  const float* W1    = (const float*)d_in[7];
  const float* b1    = (const float*)d_in[8];
  const float* W2    = (const float*)d_in[9];
  const float* b2    = (const float*)d_in[10];
  const float* Wf    = (const float*)d_in[11];
  const float* bfv   = (const float*)d_in[12];
  const float* WihD  = (const float*)d_in[13];
  const float* WhhD  = (const float*)d_in[14];
  const float* bD    = (const float*)d_in[15];
  const float* Wo    = (const float*)d_in[16];
  const float* bo    = (const float*)d_in[17];
  float* out = (float*)d_out;

  char* ws = (char*)d_ws;
  size_t off = 0;
  auto alloc = [&](size_t bytes) { size_t o = off; off = (off + bytes + 255) & ~(size_t)255; return o; };

  int*   prog = (int*)(ws + alloc(BB*32*4));       // decoder progress (line/batch)
  int*   bar  = (int*)(ws + alloc(64*4));          // workers barrier cnt/gen
  float* deg  = (float*)(ws + alloc(NNODE*4));
  float* s1   = (float*)(ws + alloc(NNODE*4));
  float* s2   = (float*)(ws + alloc(NNODE*4));
  float* gvec = (float*)(ws + alloc(128*4));
  float* csum = (float*)(ws + alloc(4));
  size_t zero_bytes = off;
  float* dinv = (float*)(ws + alloc(NNODE*4));
  float* cc   = (float*)(ws + alloc(NNODE*4));
  float* ee   = (float*)(ws + alloc(NNODE*4));
  float* mvec = (float*)(ws + alloc(128*4));
  float* hmean= (float*)(ws + alloc(BB*HH*4));
  float* xgenc= (float*)(ws + alloc((size_t)BB*SS*512*4));
  __hip_bfloat16* Ahi = (__hip_bfloat16*)(ws + alloc((size_t)BB*SS*HH*2));
  __hip_bfloat16* Alo = (__hip_bfloat16*)(ws + alloc((size_t)BB*SS*HH*2));
  __hip_bfloat16* Bhi = (__hip_bfloat16*)(ws + alloc((size_t)VV*HH*2));
  __hip_bfloat16* Blo = (__hip_bfloat16*)(ws + alloc((size_t)VV*HH*2));

  hipMemsetAsync(ws, 0, zero_bytes, stream);

  // serial xg production (tiny, ~20us)
  xg_enc_kernel<<<dim3((BB*SS)/8), dim3(256), 0, stream>>>(jin, emb, WihE, bE, xgenc);

  // front: clean enc scan + {Wo split, graph pipeline} on idle CUs
  front_kernel<<<dim3(8 + NWORK), dim3(512), 0, stream>>>(
      xgenc, WhhE, hmean, Wo, Bhi, Blo,
      esrc, edst, nids, emb, deg, dinv, s1, s2, cc, ee, csum, gvec,
      W1, b1, W2, b2, mvec, bar);

  // fused: inline-fusion + decoder scan + persistent-owner GEMM (125 owners)
  dec_gemm_kernel<<<dim3(8 + NOWN), dim3(512), 0, stream>>>(
      hmean, mvec, Wf, bfv, WihD, bD, WhhD,
      Ahi, Alo, Bhi, Blo, bo, out, prog);
}

// Round 22
// 1064.661 us; speedup vs baseline: 1.2056x; 1.0326x over previous
//
#include <hip/hip_runtime.h>
#include <hip/hip_bf16.h>
#include <stdint.h>

#define VV 32000
#define HH 128
#define BB 8
#define SS 512
#define NNODE 50000
#define NEDGE 600000
#define NWORK 120          // throttled workers (halved intensity under the scan)
#define NOWN 125           // persistent gemm owners (one per 256-col B panel)

typedef __attribute__((ext_vector_type(8))) short s16x8;
typedef __attribute__((ext_vector_type(4))) float f32x4;

__device__ __forceinline__ void workers_barrier(int* bar, int tid) {
  __syncthreads();
  if (tid == 0) {
    int g = __hip_atomic_load(&bar[32], __ATOMIC_ACQUIRE, __HIP_MEMORY_SCOPE_AGENT);
    int old = __hip_atomic_fetch_add(&bar[0], 1, __ATOMIC_ACQ_REL, __HIP_MEMORY_SCOPE_AGENT);
    if (old == NWORK-1) {
      __hip_atomic_store(&bar[0], 0, __ATOMIC_RELAXED, __HIP_MEMORY_SCOPE_AGENT);
      __hip_atomic_store(&bar[32], g+1, __ATOMIC_RELEASE, __HIP_MEMORY_SCOPE_AGENT);
    } else {
      while (__hip_atomic_load(&bar[32], __ATOMIC_ACQUIRE, __HIP_MEMORY_SCOPE_AGENT) == g)
        __builtin_amdgcn_s_sleep(32);
    }
  }
  __syncthreads();
}

__device__ __forceinline__ int ntload_i(const int* p) {
  return __builtin_nontemporal_load(p);
}
__device__ __forceinline__ float ntload_f(const float* p) {
  return __builtin_nontemporal_load(p);
}

// ---------------- embedding gather + encoder input-gate GEMM (serial, ~20us) ----
__global__ __launch_bounds__(256) void xg_enc_kernel(
    const int* __restrict__ jin, const float* __restrict__ emb,
    const float* __restrict__ Wih, const float* __restrict__ bvec,
    float* __restrict__ xg)
{
  __shared__ __align__(16) float arow[8][128];
  const int tid = threadIdx.x, blk = blockIdx.x;
  {
    int r = tid >> 5, c = (tid & 31) << 2;
    int tok = jin[blk*8 + r];
    *(float4*)&arow[r][c] = *(const float4*)&emb[(size_t)tok*HH + c];
  }
  __syncthreads();
  const int g0 = tid * 2;
  const float* w0 = Wih + (size_t)g0*HH;
  const float* w1 = w0 + HH;
  float acc0[8], acc1[8];
  #pragma unroll
  for (int r=0;r<8;r++){ acc0[r]=0.f; acc1[r]=0.f; }
  for (int k=0;k<HH;k+=4) {
    float4 wa = *(const float4*)&w0[k];
    float4 wb = *(const float4*)&w1[k];
    #pragma unroll
    for (int r=0;r<8;r++) {
      float4 av = *(const float4*)&arow[r][k];
      acc0[r] += av.x*wa.x + av.y*wa.y + av.z*wa.z + av.w*wa.w;
      acc1[r] += av.x*wb.x + av.y*wb.y + av.z*wb.z + av.w*wb.w;
    }
  }
  float bb0 = bvec[g0], bb1 = bvec[g0+1];
  #pragma unroll
  for (int r=0;r<8;r++) {
    size_t row = (size_t)blk*8 + r;
    xg[row*512 + g0]     = acc0[r] + bb0;
    xg[row*512 + g0 + 1] = acc1[r] + bb1;
  }
}

// ---------------- FRONT: clean enc scan (blocks 0-7) + workers (split + graph) ----
__global__ __launch_bounds__(512) void front_kernel(
    const float* __restrict__ xg, const float* __restrict__ WhhE, float* __restrict__ hmean,
    const float* __restrict__ Wo, __hip_bfloat16* __restrict__ Bhi, __hip_bfloat16* __restrict__ Blo,
    const int* __restrict__ esrc, const int* __restrict__ edst, const int* __restrict__ nids,
    const float* __restrict__ emb,
    float* __restrict__ deg, float* __restrict__ dinv, float* __restrict__ s1,
    float* __restrict__ s2, float* __restrict__ cc, float* __restrict__ ee,
    float* __restrict__ csum, float* __restrict__ gvec,
    const float* __restrict__ W1, const float* __restrict__ b1,
    const float* __restrict__ W2, const float* __restrict__ b2, float* __restrict__ mvec,
    int* bar)
{
  __shared__ __align__(16) char shraw[131072];   // 128KB -> 1 block/CU (isolation)
  const int bid = blockIdx.x, tid = threadIdx.x;

  if (bid < 8) {
    // ---------------- encoder scan role (round-4 proven body) -----------------
    float* h_s   = (float*)shraw;
    float* act_s = ((float*)shraw) + 128;
    const int b = bid;

    const f32x4* Wrow = (const f32x4*)(WhhE + (size_t)tid*HH);
    f32x4 w[32];
    #pragma unroll
    for (int k=0;k<32;k++) w[k] = Wrow[k];
    #pragma unroll
    for (int k=0;k<32;k++) asm volatile("" : "+v"(w[k]));

    const float* xgrow = xg + (size_t)b*SS*512;
    float xv = xgrow[tid];
    if (tid < 128) h_s[tid] = 0.f;
    float cstate = 0.f, hsum = 0.f;
    __syncthreads();

    for (int t=0;t<SS;t++) {
      int tn = (t < SS-1) ? (t+1) : t;
      float nxv = xgrow[(size_t)tn*512 + tid];
      float a0=0.f,a1=0.f,a2=0.f,a3=0.f;
      #pragma unroll
      for (int k=0;k<32;k++) {
        f32x4 hv = *(const f32x4*)&h_s[k*4];
        a0 += w[k].x*hv.x; a1 += w[k].y*hv.y;
        a2 += w[k].z*hv.z; a3 += w[k].w*hv.w;
      }
      float s = (a0+a1)+(a2+a3) + xv;
      int gid = tid >> 7;
      float act = (gid==2) ? tanhf(s) : 1.0f/(1.0f+expf(-s));
      act_s[tid] = act;
      __syncthreads();
      if (tid < 128) {
        float i_ = act_s[tid], f_ = act_s[128+tid], g_ = act_s[256+tid], o_ = act_s[384+tid];
        cstate = f_*cstate + i_*g_;
        float hh = o_*tanhf(cstate);
        h_s[tid] = hh;
        hsum += hh;
      }
      xv = nxv;
      __syncthreads();
    }
    if (tid < 128) hmean[b*HH + tid] = hsum * (1.0f/512.0f);
  } else {
    // ---------------- worker role: Wo split + graph pipeline ------------------
    const int wbid = bid - 8;
    float* red = (float*)shraw;                  // 512 reduce scratch

    // P0: split Wo -> (bf16 hi, lo), fully nt (32MB read + 16MB write stream)
    for (int i = wbid*512 + tid; i < VV*HH/4; i += NWORK*512) {
      f32x4 v = __builtin_nontemporal_load((const f32x4*)&Wo[i*4]);
      float vv[4] = {v.x, v.y, v.z, v.w};
      #pragma unroll
      for (int k=0;k<4;k++) {
        __hip_bfloat16 h = __float2bfloat16(vv[k]);
        float rem = vv[k] - __bfloat162float(h);
        __hip_bfloat16 l = __float2bfloat16(rem);
        __builtin_nontemporal_store(*(unsigned short*)&h, (unsigned short*)&Bhi[i*4+k]);
        __builtin_nontemporal_store(*(unsigned short*)&l, (unsigned short*)&Blo[i*4+k]);
      }
    }
    workers_barrier(bar, tid);
    // P1: degree (edge list read nt)
    for (int i = wbid*512 + tid; i < NEDGE; i += NWORK*512)
      atomicAdd(&deg[ntload_i(&edst[i])], 1.0f);
    workers_barrier(bar, tid);
    // P2: dinv
    for (int n = wbid*512 + tid; n < NNODE; n += NWORK*512)
      dinv[n] = 1.0f / sqrtf(ntload_f(&deg[n]) + 1.0f);
    workers_barrier(bar, tid);
    // P3: s1  (dinv gather NORMAL: 12x reuse across edges wants L2)
    for (int i = wbid*512 + tid; i < NEDGE; i += NWORK*512)
      atomicAdd(&s1[ntload_i(&esrc[i])], dinv[ntload_i(&edst[i])]);
    workers_barrier(bar, tid);
    // P4: cc + csum
    {
      float lsum = 0.f;
      for (int n = wbid*512 + tid; n < NNODE; n += NWORK*512) {
        float d = ntload_f(&dinv[n]); float v = d*ntload_f(&s1[n]) + d*d;
        cc[n] = v; lsum += v;
      }
      red[tid] = lsum; __syncthreads();
      for (int sfl=256; sfl>0; sfl>>=1) { if (tid < sfl) red[tid] += red[tid+sfl]; __syncthreads(); }
      if (tid==0) atomicAdd(csum, red[0]);
    }
    workers_barrier(bar, tid);
    // P5: s2  (cc/dinv gathers NORMAL: reuse)
    for (int i = wbid*512 + tid; i < NEDGE; i += NWORK*512) {
      int d = ntload_i(&edst[i]);
      atomicAdd(&s2[ntload_i(&esrc[i])], cc[d]*dinv[d]);
    }
    workers_barrier(bar, tid);
    // P6: ee
    for (int n = wbid*512 + tid; n < NNODE; n += NWORK*512) {
      float d = ntload_f(&dinv[n]);
      ee[n] = d*ntload_f(&s2[n]) + ntload_f(&cc[n])*d*d;
    }
    workers_barrier(bar, tid);
    // P7: gvec[j] = sum_n ee[n]*emb[nids[n]][j]  (emb rows single-pass -> nt)
    {
      int j = tid & 127, sub = tid >> 7;         // 4 n-lanes per block
      float acc = 0.f;
      for (int n = wbid*4 + sub; n < NNODE; n += NWORK*4)
        acc += ntload_f(&ee[n]) * ntload_f(&emb[(size_t)ntload_i(&nids[n])*HH + j]);
      red[tid] = acc; __syncthreads();
      if (tid < 128) atomicAdd(&gvec[j], red[tid] + red[tid+128] + red[tid+256] + red[tid+384]);
    }
    workers_barrier(bar, tid);
    // P8: graph final (block 0, full-block barriers)
    if (wbid == 0) {
      float* gs = (float*)shraw;
      float* v1 = gs + 128;
      if (tid < 128) gs[tid] = gvec[tid];
      __syncthreads();
      if (tid < 128) {
        float a = 0.f;
        for (int k=0;k<128;k++) a += gs[k]*W1[tid*128+k];
        v1[tid] = a + csum[0]*b1[tid];
      }
      __syncthreads();
      if (tid < 128) {
        float a2 = 0.f;
        for (int k=0;k<128;k++) a2 += v1[k]*W2[tid*128+k];
        mvec[tid] = a2 * (1.0f/(float)NNODE) + b2[tid];
      }
    }
  }
}

// ---------------- FUSED decoder scan + PERSISTENT-owner output GEMM ----------
// Round-20 proven config (64-step publish, 8 chunks, 64-row owner tiles) +
// round-21's good idea: the FINAL chunk (c==7) uses normal stores (scan done,
// L2 protection moot; full-line write-combining drains the tail faster).
__global__ __launch_bounds__(512) void dec_gemm_kernel(
    const float* __restrict__ hmean, const float* __restrict__ mvec,
    const float* __restrict__ Wf, const float* __restrict__ bfv,
    const float* __restrict__ Wihd, const float* __restrict__ bd,
    const float* __restrict__ Whh,
    __hip_bfloat16* __restrict__ ahi, __hip_bfloat16* __restrict__ alo,
    const __hip_bfloat16* __restrict__ Bhi, const __hip_bfloat16* __restrict__ Blo,
    const float* __restrict__ bo, float* __restrict__ out, int* __restrict__ prog)
{
  __shared__ __align__(16) char shraw[131072];   // 128KB -> 1 block/CU
  const int bid = blockIdx.x, tid = threadIdx.x;

  if (bid < 8) {
    // ---------------- decoder scan role (round-4 body + inline fusion) --------
    float* h_s   = (float*)shraw;
    float* act_s = ((float*)shraw) + 128;        // also reused as comb[256]
    float* fus   = (float*)(shraw + 4096);       // 128 floats
    const int b = bid;

    const f32x4* Wrow = (const f32x4*)(Whh + (size_t)tid*HH);
    f32x4 w[32];
    #pragma unroll
    for (int k=0;k<32;k++) w[k] = Wrow[k];
    #pragma unroll
    for (int k=0;k<32;k++) asm volatile("" : "+v"(w[k]));

    // inline fusion (bit-identical to the old fusion_kernel loop order)
    float* comb = act_s;
    if (tid < 128) comb[tid] = hmean[b*128 + tid];
    else if (tid < 256) comb[tid] = mvec[tid - 128];
    __syncthreads();
    if (tid < 128) {
      float a = 0.f;
      for (int k=0;k<256;k++) a += comb[k]*Wf[tid*256+k];
      fus[tid] = a + bfv[tid];
    }
    __syncthreads();
    float xv;
    {
      float a = 0.f;
      for (int k=0;k<128;k++) a += fus[k]*Wihd[tid*128+k];
      xv = a + bd[tid];
    }
    __syncthreads();                             // before reusing act_s
    if (tid < 128) h_s[tid] = 0.f;
    float cstate = 0.f;
    __syncthreads();

    for (int t=0;t<SS;t++) {
      float a0=0.f,a1=0.f,a2=0.f,a3=0.f;
      #pragma unroll
      for (int k=0;k<32;k++) {
        f32x4 hv = *(const f32x4*)&h_s[k*4];
        a0 += w[k].x*hv.x; a1 += w[k].y*hv.y;
        a2 += w[k].z*hv.z; a3 += w[k].w*hv.w;
      }
      float s = (a0+a1)+(a2+a3) + xv;
      int gid = tid >> 7;
      float act = (gid==2) ? tanhf(s) : 1.0f/(1.0f+expf(-s));
      act_s[tid] = act;
      __syncthreads();
      if (tid < 128) {
        float i_ = act_s[tid], f_ = act_s[128+tid], g_ = act_s[256+tid], o_ = act_s[384+tid];
        cstate = f_*cstate + i_*g_;
        float hh = o_*tanhf(cstate);
        h_s[tid] = hh;
        size_t row = (size_t)b*SS + t;
        __hip_bfloat16 hi = __float2bfloat16(hh);
        float rem = hh - __bfloat162float(hi);
        __hip_bfloat16 lo = __float2bfloat16(rem);
        __builtin_nontemporal_store(*(unsigned short*)&hi, (unsigned short*)&ahi[row*HH + tid]);
        __builtin_nontemporal_store(*(unsigned short*)&lo, (unsigned short*)&alo[row*HH + tid]);
      }
      __syncthreads();
      if ((t & 63) == 63) {                     // publish completed 64-step chunk
        __threadfence();
        __syncthreads();
        if (tid == 0)
          __hip_atomic_store(&prog[b*32], (t >> 6) + 1,
                             __ATOMIC_RELEASE, __HIP_MEMORY_SCOPE_AGENT);
      }
    }
  } else {
    // ---------------- persistent gemm owner: one 256-col panel ----------------
    short* smem = (short*)shraw;                // hi plane @0, lo plane @64KB
    const int nblk = bid - 8;                   // 0..124

    // stage B panel once (256 cols x 128 k, hi+lo), inverse-swizzled source
    const short* bsrc[2] = {
      (const short*)Bhi + (size_t)nblk*256*HH,
      (const short*)Blo + (size_t)nblk*256*HH };
    #pragma unroll
    for (int p=0;p<2;p++) {
      #pragma unroll
      for (int it=0; it<8; it++) {
        int off  = it*8192 + tid*16;
        int row  = off >> 8;
        int soff = off ^ ((row & 15) << 4);
        __builtin_amdgcn_global_load_lds(
          (const __attribute__((address_space(1))) void*)((const char*)bsrc[p] + soff),
          (__attribute__((address_space(3))) void*)((char*)smem + p*65536 + off),
          16, 0, 0);
      }
    }
    __syncthreads();

    const int lane = tid & 63;
    const int wid  = tid >> 6;
    const int wm = wid >> 2, wn = wid & 3;      // 2m x 4n waves: 32x64 each
    const int l15 = lane & 15, l4 = lane >> 4;
    const short* Ah = (const short*)ahi;
    const short* Al = (const short*)alo;

    for (int c = 0; c < 8; ++c) {
      for (int b = 0; b < 8; ++b) {
        if (tid == 0) {                         // single-lane, slow poll
          while (__hip_atomic_load(&prog[b*32], __ATOMIC_ACQUIRE,
                                   __HIP_MEMORY_SCOPE_AGENT) <= c)
            __builtin_amdgcn_s_sleep(64);
        }
        __syncthreads();

        const int mbase = b*512 + c*64 + wm*32;
        f32x4 acc[2][4] = {};
        #pragma unroll
        for (int s=0;s<4;s++) {
          s16x8 bh[4], bl[4], ah[2], al[2];
          #pragma unroll
          for (int qn=0;qn<4;qn++) {
            int rb   = wn*64 + qn*16 + l15;
            int offb = (rb*256 + s*64 + l4*16) ^ ((rb & 15) << 4);
            bh[qn] = *(const s16x8*)((const char*)smem + offb);
            bl[qn] = *(const s16x8*)((const char*)smem + 65536 + offb);
          }
          #pragma unroll
          for (int qm=0;qm<2;qm++) {
            int arow = mbase + qm*16 + l15;
            size_t aoff = (size_t)arow*HH + s*32 + l4*8;
            ah[qm] = *(const s16x8*)(Ah + aoff);    // NORMAL loads: A reuse wants L2
            al[qm] = *(const s16x8*)(Al + aoff);
          }
          #pragma unroll
          for (int qm=0;qm<2;qm++) {
            #pragma unroll
            for (int qn=0;qn<4;qn++) {
              acc[qm][qn] = __builtin_amdgcn_mfma_f32_16x16x32_bf16(bh[qn], ah[qm], acc[qm][qn], 0,0,0);
              acc[qm][qn] = __builtin_amdgcn_mfma_f32_16x16x32_bf16(bl[qn], ah[qm], acc[qm][qn], 0,0,0);
              acc[qm][qn] = __builtin_amdgcn_mfma_f32_16x16x32_bf16(bh[qn], al[qm], acc[qm][qn], 0,0,0);
            }
          }
        }
        if (c == 7) {                           // final chunk: scan done -> normal
          #pragma unroll
          for (int qm=0;qm<2;qm++) {
            int row = mbase + qm*16 + l15;
            #pragma unroll
            for (int qn=0;qn<4;qn++) {
              int colb = nblk*256 + wn*64 + qn*16 + l4*4;
              f32x4 bv = *(const f32x4*)&bo[colb];
              f32x4 oo = acc[qm][qn] + bv;
              *(f32x4*)&out[(size_t)row*VV + colb] = oo;
            }
          }
        } else {                                // nt: protect scan's L2
          #pragma unroll
          for (int qm=0;qm<2;qm++) {
            int row = mbase + qm*16 + l15;
            #pragma unroll
            for (int qn=0;qn<4;qn++) {
              int colb = nblk*256 + wn*64 + qn*16 + l4*4;
              f32x4 bv = *(const f32x4*)&bo[colb];
              f32x4 oo = acc[qm][qn] + bv;
              __builtin_nontemporal_store(oo, (f32x4*)&out[(size_t)row*VV + colb]);
            }
          }
        }
      }
    }
  }
}

// ---------------- launch ----------------
extern "C" void kernel_launch(void* const* d_in, const int* in_sizes, int n_in,
                              void* d_out, int out_size, void* d_ws, size_t ws_size,
                              hipStream_t stream)
{
  (void)in_sizes; (void)n_in; (void)out_size; (void)ws_size;
  const int*   jin   = (const int*)d_in[0];
  const int*   nids  = (const int*)d_in[1];
  const int*   esrc  = (const int*)d_in[2];
  const int*   edst  = esrc + NEDGE;
  const float* emb   = (const float*)d_in[3];
  const float* WihE  = (const float*)d_in[4];
  const float* WhhE  = (const float*)d_in[5];
  const float* bE    = (const float*)d_in[6];
  const float* W1    = (const float*)d_in[7];
  const float* b1    = (const float*)d_in[8];
  const float* W2    = (const float*)d_in[9];
  const float* b2    = (const float*)d_in[10];
  const float* Wf    = (const float*)d_in[11];
  const float* bfv   = (const float*)d_in[12];
  const float* WihD  = (const float*)d_in[13];
  const float* WhhD  = (const float*)d_in[14];
  const float* bD    = (const float*)d_in[15];
  const float* Wo    = (const float*)d_in[16];
  const float* bo    = (const float*)d_in[17];
  float* out = (float*)d_out;

  char* ws = (char*)d_ws;
  size_t off = 0;
  auto alloc = [&](size_t bytes) { size_t o = off; off = (off + bytes + 255) & ~(size_t)255; return o; };

  int*   prog = (int*)(ws + alloc(BB*32*4));       // decoder progress (line/batch)
  int*   bar  = (int*)(ws + alloc(64*4));          // workers barrier cnt/gen
  float* deg  = (float*)(ws + alloc(NNODE*4));
  float* s1   = (float*)(ws + alloc(NNODE*4));
  float* s2   = (float*)(ws + alloc(NNODE*4));
  float* gvec = (float*)(ws + alloc(128*4));
  float* csum = (float*)(ws + alloc(4));
  size_t zero_bytes = off;
  float* dinv = (float*)(ws + alloc(NNODE*4));
  float* cc   = (float*)(ws + alloc(NNODE*4));
  float* ee   = (float*)(ws + alloc(NNODE*4));
  float* mvec = (float*)(ws + alloc(128*4));
  float* hmean= (float*)(ws + alloc(BB*HH*4));
  float* xgenc= (float*)(ws + alloc((size_t)BB*SS*512*4));
  __hip_bfloat16* Ahi = (__hip_bfloat16*)(ws + alloc((size_t)BB*SS*HH*2));
  __hip_bfloat16* Alo = (__hip_bfloat16*)(ws + alloc((size_t)BB*SS*HH*2));
  __hip_bfloat16* Bhi = (__hip_bfloat16*)(ws + alloc((size_t)VV*HH*2));
  __hip_bfloat16* Blo = (__hip_bfloat16*)(ws + alloc((size_t)VV*HH*2));

  hipMemsetAsync(ws, 0, zero_bytes, stream);

  // serial xg production (tiny, ~20us)
  xg_enc_kernel<<<dim3((BB*SS)/8), dim3(256), 0, stream>>>(jin, emb, WihE, bE, xgenc);

  // front: clean enc scan + {Wo split, graph pipeline} on idle CUs
  front_kernel<<<dim3(8 + NWORK), dim3(512), 0, stream>>>(
      xgenc, WhhE, hmean, Wo, Bhi, Blo,
      esrc, edst, nids, emb, deg, dinv, s1, s2, cc, ee, csum, gvec,
      W1, b1, W2, b2, mvec, bar);

  // fused: inline-fusion + decoder scan + persistent-owner GEMM (125 owners)
  dec_gemm_kernel<<<dim3(8 + NOWN), dim3(512), 0, stream>>>(
      hmean, mvec, Wf, bfv, WihD, bD, WhhD,
      Ahi, Alo, Bhi, Blo, bo, out, prog);
}